// Round 9
// baseline (5471.528 us; speedup 1.0000x reference)
//
#include <hip/hip_runtime.h>
#include <hip/hip_bf16.h>
#include <math.h>

namespace {

constexpr int B  = 8;
constexpr int N  = 2048;     // power of two: n = p & 2047, b = p >> 11
constexpr int K  = 20;
constexpr int C1 = 64, C2 = 128, C3 = 256;
constexpr int NSLICE = 64;
constexpr double COUNT = 327680.0;   // B*N*K
constexpr double BNEPS = 1e-5;

// ---- workspace layout (bytes) ----
constexpr size_t OFF_IDX1  = 0;                                  // B*N*K int
constexpr size_t OFF_IDX2  = OFF_IDX1 + (size_t)B*N*K*4;         // B*N*K int
constexpr size_t OFF_X1D   = OFF_IDX2 + (size_t)B*N*K*4;         // B*N*C1 f64
constexpr size_t OFF_X2D   = OFF_X1D  + (size_t)B*N*C1*8;        // B*N*C2 f64
constexpr size_t OFF_STATS = OFF_X2D  + (size_t)B*N*C2*8;        // 2*NSLICE*C3 f64
constexpr size_t OFF_MI    = OFF_STATS+ (size_t)2*NSLICE*C3*8;   // 2*C3 f64
constexpr size_t OFF_X2F   = OFF_MI   + 4096;                    // B*N*C2 f32
constexpr size_t OFF_XX2F  = OFF_X2F  + (size_t)B*N*C2*4;        // B*N f32
constexpr size_t OFF_DIST  = OFF_XX2F + (size_t)B*N*4;           // B*N*N f32 (all batches)
// total = OFF_DIST + 134217728 ≈ 162 MB

// ---- strict-rounding f32 helpers (block FMA contraction / reassociation) ----
__device__ __forceinline__ float fmul32(float a, float b){ return __fmul_rn(a,b); }
__device__ __forceinline__ float fadd32(float a, float b){ return __fadd_rn(a,b); }
__device__ __forceinline__ float fsub32(float a, float b){ return __fsub_rn(a,b); }

// ---- per-thread insertion top-20 on f32 (largest, ties keep lowest index) ----
__device__ __forceinline__ void insert_candidatef(float v, int j,
                                                  float (&best)[K], int (&bidx)[K]) {
  if (v > best[K-1]) {
    best[K-1] = v; bidx[K-1] = j;
    #pragma unroll
    for (int i = K-1; i >= 1; --i) {
      if (best[i] > best[i-1]) {
        float tv = best[i]; best[i] = best[i-1]; best[i-1] = tv;
        int   ti = bidx[i]; bidx[i] = bidx[i-1]; bidx[i-1] = ti;
      }
    }
  }
}

// ---- kNN on 3-D coords, numpy-f32-faithful (BIT-FROZEN) ----
__global__ __launch_bounds__(64) void knn_xyz_f32(const float* __restrict__ x,
                                                  int* __restrict__ idxo) {
  int row = blockIdx.x * 64 + threadIdx.x;   // grid = B*N/64
  int b = row >> 11, n = row & (N - 1);
  const float* xb = x + (size_t)b * N * 3;
  float xi0 = xb[(size_t)n*3], xi1 = xb[(size_t)n*3+1], xi2 = xb[(size_t)n*3+2];
  float xxi = fadd32(fadd32(fmul32(xi0,xi0), fmul32(xi1,xi1)), fmul32(xi2,xi2));
  float best[K]; int bidx[K];
  #pragma unroll
  for (int i = 0; i < K; ++i) { best[i] = -INFINITY; bidx[i] = 0; }
  for (int j = 0; j < N; ++j) {
    float a = xb[(size_t)j*3], c = xb[(size_t)j*3+1], d = xb[(size_t)j*3+2];
    float xxj   = fadd32(fadd32(fmul32(a,a), fmul32(c,c)), fmul32(d,d));
    float inner = fadd32(fadd32(fmul32(xi0,a), fmul32(xi1,c)), fmul32(xi2,d));
    float v = fsub32(fsub32(fmul32(2.f, inner), xxi), xxj);
    insert_candidatef(v, j, best, bidx);
  }
  int* o = idxo + (size_t)row * K;
  #pragma unroll
  for (int i = 0; i < K; ++i) o[i] = bidx[i];
}

// ---- x2 -> f32 copy + numpy pairwise(n=128) sum of squares (BIT-FROZEN) ----
__global__ __launch_bounds__(64) void xx2f_kernel(const double* __restrict__ x2d,
                                                  float* __restrict__ x2f,
                                                  float* __restrict__ xx2f) {
  int row = blockIdx.x * 64 + threadIdx.x;   // grid = B*N/64
  const double* src = x2d + (size_t)row * C2;
  float* dst = x2f + (size_t)row * C2;
  float sq[C2];
  #pragma unroll 8
  for (int c = 0; c < C2; ++c) {
    float v = (float)src[c];
    dst[c] = v;
    sq[c] = fmul32(v, v);
  }
  float r0=sq[0], r1=sq[1], r2=sq[2], r3=sq[3], r4=sq[4], r5=sq[5], r6=sq[6], r7=sq[7];
  #pragma unroll
  for (int i = 8; i < 128; i += 8) {
    r0 = fadd32(r0, sq[i+0]); r1 = fadd32(r1, sq[i+1]);
    r2 = fadd32(r2, sq[i+2]); r3 = fadd32(r3, sq[i+3]);
    r4 = fadd32(r4, sq[i+4]); r5 = fadd32(r5, sq[i+5]);
    r6 = fadd32(r6, sq[i+6]); r7 = fadd32(r7, sq[i+7]);
  }
  xx2f[row] = fadd32(fadd32(fadd32(r0,r1), fadd32(r2,r3)),
                     fadd32(fadd32(r4,r5), fadd32(r6,r7)));
}

// ---- all-batch neg-distance matrix, f32 sequential (BIT-FROZEN inner) ----
__global__ __launch_bounds__(256) void dist_f32_kernel(const float* __restrict__ x2f,
                                                       const float* __restrict__ xx2f,
                                                       float* __restrict__ dist) {
  int bz = blockIdx.z;
  const float* x2b  = x2f  + (size_t)bz * N * C2;
  const float* xx2b = xx2f + (size_t)bz * N;
  float* db = dist + (size_t)bz * N * N;
  int ti = blockIdx.y * 64;
  int tj = blockIdx.x * 64;
  int tid = threadIdx.x;
  int tr = tid >> 4, tc = tid & 15;
  __shared__ float A[64][9], Bm[64][9];
  float acc[4][4];
  #pragma unroll
  for (int u = 0; u < 4; ++u)
    #pragma unroll
    for (int v = 0; v < 4; ++v) acc[u][v] = 0.f;
  for (int c0 = 0; c0 < C2; c0 += 8) {
    for (int i = tid; i < 512; i += 256) {
      int r = i >> 3, c = i & 7;
      A[r][c]  = x2b[(size_t)(ti + r)*C2 + c0 + c];
      Bm[r][c] = x2b[(size_t)(tj + r)*C2 + c0 + c];
    }
    __syncthreads();
    #pragma unroll
    for (int c = 0; c < 8; ++c) {       // ascending c: exact sequential order
      float a[4], bv[4];
      #pragma unroll
      for (int u = 0; u < 4; ++u) a[u] = A[tr*4 + u][c];
      #pragma unroll
      for (int v = 0; v < 4; ++v) bv[v] = Bm[tc*4 + v][c];
      #pragma unroll
      for (int u = 0; u < 4; ++u)
        #pragma unroll
        for (int v = 0; v < 4; ++v)
          acc[u][v] = fadd32(acc[u][v], fmul32(a[u], bv[v]));
    }
    __syncthreads();
  }
  #pragma unroll
  for (int u = 0; u < 4; ++u) {
    int i = ti + tr*4 + u;
    float xxi = xx2b[i];
    #pragma unroll
    for (int v = 0; v < 4; ++v) {
      int j = tj + tc*4 + v;
      db[(size_t)i*N + j] = fsub32(fsub32(fmul32(2.f, acc[u][v]), xxi), xx2b[j]);
    }
  }
}

// ---- all-batch top-k from f32 distance rows (BIT-FROZEN) ----
__global__ __launch_bounds__(64) void knn_feat_f32(const float* __restrict__ dist,
                                                   int* __restrict__ idxo) {
  int row = blockIdx.x * 64 + threadIdx.x;   // grid = B*N/64
  const float* dr = dist + (size_t)row * N;
  float best[K]; int bidx[K];
  #pragma unroll
  for (int i = 0; i < K; ++i) { best[i] = -INFINITY; bidx[i] = 0; }
  for (int j = 0; j < N; ++j) insert_candidatef(dr[j], j, best, bidx);
  int* o = idxo + (size_t)row * K;
  #pragma unroll
  for (int i = 0; i < K; ++i) o[i] = bidx[i];
}

// ---- layer 1 (two-pass, f64): geometry + conv1 (BIT-FROZEN) ----
template<int PASS>
__global__ __launch_bounds__(64) void l1_kernel(
    const float* __restrict__ x, const float* __restrict__ nrm,
    const float* __restrict__ w1, const int* __restrict__ idx1,
    double* __restrict__ sS, double* __restrict__ sQ,
    const double* __restrict__ mid, const float* __restrict__ g1, const float* __restrict__ b1,
    double* __restrict__ x1d, float* __restrict__ out448,
    float* __restrict__ outR1, float* __restrict__ outR2) {
  int p = blockIdx.x;
  int tid = threadIdx.x;
  int b = p >> 11, n = p & (N - 1);
  __shared__ float  wl[C1 * 9];
  __shared__ double rotd[K][3];
  __shared__ double fld[K][9];
  for (int i = tid; i < C1 * 9; i += 64) wl[i] = w1[i];
  const float* xb = x + (size_t)b * N * 3;
  double nx = nrm[(size_t)p*3], ny = nrm[(size_t)p*3+1], nz = nrm[(size_t)p*3+2];
  double vx = ny, vy = -nx;
  double s = 1.0 / fmax(1.0 + nz, 1e-8);
  double vxy = vx * vy;
  double R1v[9];
  R1v[0] = 1.0 - s*(vy*vy); R1v[1] = s*vxy;           R1v[2] = vy;
  R1v[3] = s*vxy;           R1v[4] = 1.0 - s*(vx*vx); R1v[5] = -vx;
  R1v[6] = -vy;             R1v[7] = vx;              R1v[8] = 1.0 - s*(vx*vx + vy*vy);
  double xi0 = xb[(size_t)n*3], xi1 = xb[(size_t)n*3+1], xi2 = xb[(size_t)n*3+2];
  if (tid < K) {
    int j = idx1[(size_t)p*K + tid];
    double d0 = (double)xb[(size_t)j*3]   - xi0;
    double d1 = (double)xb[(size_t)j*3+1] - xi1;
    double d2 = (double)xb[(size_t)j*3+2] - xi2;
    rotd[tid][0] = R1v[0]*d0 + R1v[1]*d1 + R1v[2]*d2;
    rotd[tid][1] = R1v[3]*d0 + R1v[4]*d1 + R1v[5]*d2;
    rotd[tid][2] = R1v[6]*d0 + R1v[7]*d1 + R1v[8]*d2;
  }
  __syncthreads();
  double mx = 0.0, my = 0.0;
  #pragma unroll
  for (int k = 0; k < K; ++k) { mx += rotd[k][0]; my += rotd[k][1]; }
  mx /= 20.0; my /= 20.0;
  double r = sqrt(mx*mx + my*my);
  double ct = 1.0, st = 0.0;
  if (r > 0.0) { ct = mx / r; st = my / r; }   // cos/sin of atan2(my,mx)
  if (tid < K) {
    double r0 = rotd[tid][0], r1 = rotd[tid][1], r2 = rotd[tid][2];
    double a0 = ct*r0 + st*r1;
    double a1 = ct*r1 - st*r0;
    fld[tid][0] = a0;  fld[tid][1] = a1;   fld[tid][2] = r2;
    fld[tid][3] = a0;  fld[tid][4] = -a1;  fld[tid][5] = r2;   // xz-mirror
    fld[tid][6] = xi0; fld[tid][7] = xi1;  fld[tid][8] = xi2;  // x_rep
  }
  if (PASS == 0 && tid == 0) {
    float* o1 = outR1 + (size_t)p * 9;
    #pragma unroll
    for (int i = 0; i < 9; ++i) o1[i] = (float)R1v[i];
    float* o2 = outR2 + (size_t)p * 9;
    o2[0] = (float)ct;  o2[1] = (float)st; o2[2] = 0.f;
    o2[3] = (float)-st; o2[4] = (float)ct; o2[5] = 0.f;
    o2[6] = 0.f;        o2[7] = 0.f;       o2[8] = 1.f;
  }
  __syncthreads();
  int o = tid;
  if (PASS == 0) {
    double sum = 0., sq = 0.;
    #pragma unroll
    for (int k = 0; k < K; ++k) {
      double h = 0.;
      #pragma unroll
      for (int c = 0; c < 9; ++c) h = fma((double)wl[o*9 + c], fld[k][c], h);
      sum += h; sq += h*h;
    }
    int slice = p & (NSLICE - 1);
    atomicAdd(&sS[slice*C3 + o], sum);
    atomicAdd(&sQ[slice*C3 + o], sq);
  } else {
    double m = mid[o], is = mid[C3 + o];
    double g = g1[o], bb = b1[o];
    double mxv = -INFINITY;
    #pragma unroll
    for (int k = 0; k < K; ++k) {
      double h = 0.;
      #pragma unroll
      for (int c = 0; c < 9; ++c) h = fma((double)wl[o*9 + c], fld[k][c], h);
      double y = ((h - m) * is) * g + bb;
      y = y > 0.0 ? y : 0.2 * y;
      mxv = fmax(mxv, y);
    }
    x1d[(size_t)p*C1 + o] = mxv;
    out448[(size_t)p*448 + o] = (float)mxv;
  }
}

// ---- conv2 (two-pass, f64): LDS-staged gather, register-blocked NOUT=2.
// BIT-EXACT per-acc sequence: phase1 c=0..63 fma(w[c], dif[c]) ascending,
// phase2 c=0..63 fma(w[64+c], xi[c]) ascending. 64 threads; o = tid, tid+64. ----
template<int PASS>
__global__ __launch_bounds__(64) void conv2_kernel(
    const double* __restrict__ x1d, const int* __restrict__ idx,
    const float* __restrict__ w,
    double* __restrict__ sS, double* __restrict__ sQ,
    const double* __restrict__ mid, const float* __restrict__ gam, const float* __restrict__ bet,
    double* __restrict__ x2d, float* __restrict__ out448) {
  int p = blockIdx.x;
  int tid = threadIdx.x;
  int b = p >> 11;
  __shared__ double difL[K][C1];
  __shared__ double xiL[C1];
  __shared__ int jidx[K];
  if (tid < K) jidx[tid] = idx[(size_t)p*K + tid];
  xiL[tid] = x1d[(size_t)p*C1 + tid];
  __syncthreads();
  #pragma unroll 1
  for (int i = tid; i < K*C1; i += 64) {
    int k = i >> 6, c = i & 63;
    difL[k][c] = x1d[((size_t)b*N + jidx[k])*C1 + c] - xiL[c];
  }
  __syncthreads();
  const float* wr0 = w + (size_t)tid * (2*C1);
  const float* wr1 = w + (size_t)(tid + 64) * (2*C1);
  double acc0[K], acc1[K];
  #pragma unroll
  for (int k = 0; k < K; ++k) { acc0[k] = 0.0; acc1[k] = 0.0; }
  // phase 1: diff operand, c ascending per acc
  #pragma unroll 1
  for (int c0 = 0; c0 < C1; c0 += 8) {
    double w0[8], w1v[8];
    #pragma unroll
    for (int i = 0; i < 8; ++i) { w0[i] = (double)wr0[c0+i]; w1v[i] = (double)wr1[c0+i]; }
    #pragma unroll
    for (int k = 0; k < K; ++k) {
      double dv[8];
      #pragma unroll
      for (int i = 0; i < 8; ++i) dv[i] = difL[k][c0+i];
      #pragma unroll
      for (int i = 0; i < 8; ++i) acc0[k] = fma(w0[i], dv[i], acc0[k]);
      #pragma unroll
      for (int i = 0; i < 8; ++i) acc1[k] = fma(w1v[i], dv[i], acc1[k]);
    }
  }
  // phase 2: x_rep operand, c ascending per acc
  #pragma unroll 1
  for (int c0 = 0; c0 < C1; c0 += 8) {
    double w0[8], w1v[8], xv[8];
    #pragma unroll
    for (int i = 0; i < 8; ++i) {
      w0[i] = (double)wr0[C1+c0+i]; w1v[i] = (double)wr1[C1+c0+i]; xv[i] = xiL[c0+i];
    }
    #pragma unroll
    for (int k = 0; k < K; ++k) {
      #pragma unroll
      for (int i = 0; i < 8; ++i) acc0[k] = fma(w0[i], xv[i], acc0[k]);
      #pragma unroll
      for (int i = 0; i < 8; ++i) acc1[k] = fma(w1v[i], xv[i], acc1[k]);
    }
  }
  if (PASS == 0) {
    double s0 = 0., q0 = 0., s1 = 0., q1 = 0.;
    #pragma unroll
    for (int k = 0; k < K; ++k) {
      s0 += acc0[k]; q0 += acc0[k]*acc0[k];
      s1 += acc1[k]; q1 += acc1[k]*acc1[k];
    }
    int slice = p & (NSLICE - 1);
    atomicAdd(&sS[slice*C3 + tid], s0);
    atomicAdd(&sQ[slice*C3 + tid], q0);
    atomicAdd(&sS[slice*C3 + tid + 64], s1);
    atomicAdd(&sQ[slice*C3 + tid + 64], q1);
  } else {
    double m0 = mid[tid], is0 = mid[C3 + tid];
    double m1 = mid[tid+64], is1 = mid[C3 + tid+64];
    double g0 = gam[tid], bb0 = bet[tid];
    double g1v = gam[tid+64], bb1 = bet[tid+64];
    double mx0 = -INFINITY, mx1 = -INFINITY;
    #pragma unroll
    for (int k = 0; k < K; ++k) {
      double y0 = ((acc0[k] - m0) * is0) * g0 + bb0;
      y0 = y0 > 0.0 ? y0 : 0.2 * y0;
      mx0 = fmax(mx0, y0);
      double y1 = ((acc1[k] - m1) * is1) * g1v + bb1;
      y1 = y1 > 0.0 ? y1 : 0.2 * y1;
      mx1 = fmax(mx1, y1);
    }
    x2d[(size_t)p*C2 + tid] = mx0;
    x2d[(size_t)p*C2 + tid + 64] = mx1;
    out448[(size_t)p*448 + C1 + tid] = (float)mx0;
    out448[(size_t)p*448 + C1 + tid + 64] = (float)mx1;
  }
}

// ---- conv3 (two-pass, f32, value path): folded + LDS-staged, NOUT=4.
// 64 threads; o = tid + 64*no. Per-acc fmaf order unchanged (c ascending). ----
template<int PASS>
__global__ __launch_bounds__(64) void conv3_kernel(
    const float* __restrict__ x2f, const int* __restrict__ idx,
    const float* __restrict__ w,
    double* __restrict__ sS, double* __restrict__ sQ,
    const double* __restrict__ mid, const float* __restrict__ gam, const float* __restrict__ bet,
    float* __restrict__ out448) {
  int p = blockIdx.x;
  int tid = threadIdx.x;
  int b = p >> 11;
  __shared__ float xjL[K][C2];
  __shared__ float xiL[C2];
  __shared__ int jidx[K];
  if (tid < K) jidx[tid] = idx[(size_t)p*K + tid];
  xiL[tid] = x2f[(size_t)p*C2 + tid];
  xiL[tid + 64] = x2f[(size_t)p*C2 + tid + 64];
  __syncthreads();
  #pragma unroll 1
  for (int i = tid; i < K*C2; i += 64) {
    int k = i >> 7, c = i & 127;
    xjL[k][c] = x2f[((size_t)b*N + jidx[k])*C2 + c];
  }
  __syncthreads();
  const float* wr0 = w + (size_t)(tid)       * (2*C2);
  const float* wr1 = w + (size_t)(tid + 64)  * (2*C2);
  const float* wr2 = w + (size_t)(tid + 128) * (2*C2);
  const float* wr3 = w + (size_t)(tid + 192) * (2*C2);
  float base0 = 0.f, base1 = 0.f, base2 = 0.f, base3 = 0.f;
  #pragma unroll 1
  for (int c0 = 0; c0 < C2; c0 += 8) {
    #pragma unroll
    for (int i = 0; i < 8; ++i) {
      float xv = xiL[c0+i];
      base0 = fmaf(wr0[C2+c0+i] - wr0[c0+i], xv, base0);
      base1 = fmaf(wr1[C2+c0+i] - wr1[c0+i], xv, base1);
      base2 = fmaf(wr2[C2+c0+i] - wr2[c0+i], xv, base2);
      base3 = fmaf(wr3[C2+c0+i] - wr3[c0+i], xv, base3);
    }
  }
  float acc0[K], acc1[K], acc2[K], acc3[K];
  #pragma unroll
  for (int k = 0; k < K; ++k) { acc0[k] = base0; acc1[k] = base1; acc2[k] = base2; acc3[k] = base3; }
  #pragma unroll 1
  for (int c0 = 0; c0 < C2; c0 += 8) {
    float w0[8], w1v[8], w2v[8], w3v[8];
    #pragma unroll
    for (int i = 0; i < 8; ++i) {
      w0[i] = wr0[c0+i]; w1v[i] = wr1[c0+i]; w2v[i] = wr2[c0+i]; w3v[i] = wr3[c0+i];
    }
    #pragma unroll
    for (int k = 0; k < K; ++k) {
      float xv[8];
      #pragma unroll
      for (int i = 0; i < 8; ++i) xv[i] = xjL[k][c0+i];
      #pragma unroll
      for (int i = 0; i < 8; ++i) acc0[k] = fmaf(w0[i], xv[i], acc0[k]);
      #pragma unroll
      for (int i = 0; i < 8; ++i) acc1[k] = fmaf(w1v[i], xv[i], acc1[k]);
      #pragma unroll
      for (int i = 0; i < 8; ++i) acc2[k] = fmaf(w2v[i], xv[i], acc2[k]);
      #pragma unroll
      for (int i = 0; i < 8; ++i) acc3[k] = fmaf(w3v[i], xv[i], acc3[k]);
    }
  }
  if (PASS == 0) {
    double s0=0., q0=0., s1=0., q1=0., s2=0., q2=0., s3=0., q3=0.;
    #pragma unroll
    for (int k = 0; k < K; ++k) {
      double h0 = (double)acc0[k]; s0 += h0; q0 += h0*h0;
      double h1 = (double)acc1[k]; s1 += h1; q1 += h1*h1;
      double h2 = (double)acc2[k]; s2 += h2; q2 += h2*h2;
      double h3 = (double)acc3[k]; s3 += h3; q3 += h3*h3;
    }
    int slice = p & (NSLICE - 1);
    atomicAdd(&sS[slice*C3 + tid], s0);
    atomicAdd(&sQ[slice*C3 + tid], q0);
    atomicAdd(&sS[slice*C3 + tid + 64], s1);
    atomicAdd(&sQ[slice*C3 + tid + 64], q1);
    atomicAdd(&sS[slice*C3 + tid + 128], s2);
    atomicAdd(&sQ[slice*C3 + tid + 128], q2);
    atomicAdd(&sS[slice*C3 + tid + 192], s3);
    atomicAdd(&sQ[slice*C3 + tid + 192], q3);
  } else {
    float* ob = out448 + (size_t)p*448 + C1 + C2;
    #pragma unroll
    for (int no = 0; no < 4; ++no) {
      int o = tid + no*64;
      float m = (float)mid[o], is = (float)mid[C3 + o];
      float g = gam[o], bb = bet[o];
      float mxv = -INFINITY;
      const float* ac = (no == 0) ? acc0 : (no == 1) ? acc1 : (no == 2) ? acc2 : acc3;
      #pragma unroll
      for (int k = 0; k < K; ++k) {
        float y = (ac[k] - m) * is * g + bb;
        y = y > 0.f ? y : 0.2f * y;
        mxv = fmaxf(mxv, y);
      }
      ob[o] = mxv;
    }
  }
}

// ---- finalize BN stats (f64) ----
__global__ void finalize_stats(const double* __restrict__ sS, const double* __restrict__ sQ,
                               double* __restrict__ mid, int C) {
  int o = threadIdx.x;
  if (o >= C) return;
  double s = 0., q = 0.;
  for (int i = 0; i < NSLICE; ++i) { s += sS[i*C3 + o]; q += sQ[i*C3 + o]; }
  double m = s / COUNT;
  double v = q / COUNT - m*m;
  mid[o] = m;
  mid[C3 + o] = 1.0 / sqrt(v + BNEPS);
}

} // namespace

extern "C" void kernel_launch(void* const* d_in, const int* in_sizes, int n_in,
                              void* d_out, int out_size, void* d_ws, size_t ws_size,
                              hipStream_t stream) {
  (void)in_sizes; (void)n_in; (void)out_size; (void)ws_size;
  const float* x   = (const float*)d_in[0];
  const float* nrm = (const float*)d_in[1];
  const float* w1  = (const float*)d_in[2];
  const float* g1  = (const float*)d_in[3];
  const float* b1  = (const float*)d_in[4];
  const float* w2  = (const float*)d_in[5];
  const float* g2  = (const float*)d_in[6];
  const float* b2  = (const float*)d_in[7];
  const float* w3  = (const float*)d_in[8];
  const float* g3  = (const float*)d_in[9];
  const float* b3  = (const float*)d_in[10];
  float* out = (float*)d_out;
  char*  ws  = (char*)d_ws;

  int*    idx1 = (int*)(ws + OFF_IDX1);
  int*    idx2 = (int*)(ws + OFF_IDX2);
  double* x1d  = (double*)(ws + OFF_X1D);
  double* x2d  = (double*)(ws + OFF_X2D);
  double* sS   = (double*)(ws + OFF_STATS);
  double* sQ   = sS + (size_t)NSLICE * C3;
  double* mid  = (double*)(ws + OFF_MI);
  float*  x2f  = (float*)(ws + OFF_X2F);
  float*  xx2f = (float*)(ws + OFF_XX2F);
  float*  dist = (float*)(ws + OFF_DIST);   // all batches

  float* outR1 = out + (size_t)B * N * 448;
  float* outR2 = outR1 + (size_t)B * N * 9;

  // kNN1 — numpy-f32-faithful formula
  knn_xyz_f32<<<B*N/64, 64, 0, stream>>>(x, idx1);

  // layer 1 (f64 two-pass)
  hipMemsetAsync(sS, 0, (size_t)2*NSLICE*C3*sizeof(double), stream);
  l1_kernel<0><<<B*N, 64, 0, stream>>>(x, nrm, w1, idx1, sS, sQ, nullptr, nullptr, nullptr,
                                       nullptr, nullptr, outR1, outR2);
  finalize_stats<<<1, C3, 0, stream>>>(sS, sQ, mid, C1);
  l1_kernel<1><<<B*N, 64, 0, stream>>>(x, nrm, w1, idx1, nullptr, nullptr, mid, g1, b1,
                                       x1d, out, outR1, outR2);

  // layer 2 (f64 two-pass, LDS-staged, register-blocked, bit-exact op order)
  hipMemsetAsync(sS, 0, (size_t)2*NSLICE*C3*sizeof(double), stream);
  conv2_kernel<0><<<B*N, 64, 0, stream>>>(x1d, idx1, w2, sS, sQ, nullptr, nullptr, nullptr,
                                          nullptr, nullptr);
  finalize_stats<<<1, C3, 0, stream>>>(sS, sQ, mid, C2);
  conv2_kernel<1><<<B*N, 64, 0, stream>>>(x1d, idx1, w2, nullptr, nullptr, mid, g2, b2,
                                          x2d, out);

  // kNN2 — numpy-f32-faithful, all batches fused
  xx2f_kernel<<<B*N/64, 64, 0, stream>>>(x2d, x2f, xx2f);
  dist_f32_kernel<<<dim3(N/64, N/64, B), 256, 0, stream>>>(x2f, xx2f, dist);
  knn_feat_f32<<<B*N/64, 64, 0, stream>>>(dist, idx2);

  // layer 3 (f32 two-pass, folded, LDS-staged, register-blocked, value path)
  hipMemsetAsync(sS, 0, (size_t)2*NSLICE*C3*sizeof(double), stream);
  conv3_kernel<0><<<B*N, 64, 0, stream>>>(x2f, idx2, w3, sS, sQ, nullptr, nullptr, nullptr,
                                          nullptr);
  finalize_stats<<<1, C3, 0, stream>>>(sS, sQ, mid, C3);
  conv3_kernel<1><<<B*N, 64, 0, stream>>>(x2f, idx2, w3, nullptr, nullptr, mid, g3, b3,
                                          out);
}

// Round 10
// 3434.146 us; speedup vs baseline: 1.5933x; 1.5933x over previous
//
#include <hip/hip_runtime.h>
#include <hip/hip_bf16.h>
#include <math.h>

namespace {

constexpr int B  = 8;
constexpr int N  = 2048;     // power of two: n = p & 2047, b = p >> 11
constexpr int K  = 20;
constexpr int C1 = 64, C2 = 128, C3 = 256;
constexpr int NSLICE = 64;
constexpr double COUNT = 327680.0;   // B*N*K
constexpr double BNEPS = 1e-5;

// ---- workspace layout (bytes) ----
constexpr size_t OFF_IDX1  = 0;                                  // B*N*K int
constexpr size_t OFF_IDX2  = OFF_IDX1 + (size_t)B*N*K*4;         // B*N*K int
constexpr size_t OFF_X1D   = OFF_IDX2 + (size_t)B*N*K*4;         // B*N*C1 f64
constexpr size_t OFF_X2D   = OFF_X1D  + (size_t)B*N*C1*8;        // B*N*C2 f64
constexpr size_t OFF_STATS = OFF_X2D  + (size_t)B*N*C2*8;        // 2*NSLICE*C3 f64
constexpr size_t OFF_MI    = OFF_STATS+ (size_t)2*NSLICE*C3*8;   // 2*C3 f64
constexpr size_t OFF_X2F   = OFF_MI   + 4096;                    // B*N*C2 f32
constexpr size_t OFF_XX2F  = OFF_X2F  + (size_t)B*N*C2*4;        // B*N f32
constexpr size_t OFF_BIG   = OFF_XX2F + (size_t)B*N*4;           // shared big region
// big region holds, strictly sequentially: h2 f64 (335.5MB) -> dist f32 (134MB) -> h3 f32 (335.5MB)
constexpr size_t BIG_FAST  = (size_t)B*N*K*C2*8;                 // 335,544,320
constexpr size_t NEED_FAST = OFF_BIG + BIG_FAST;
constexpr size_t NEED_SLOW = OFF_BIG + (size_t)B*N*N*4;          // dist only

// ---- strict-rounding f32 helpers (block FMA contraction / reassociation) ----
__device__ __forceinline__ float fmul32(float a, float b){ return __fmul_rn(a,b); }
__device__ __forceinline__ float fadd32(float a, float b){ return __fadd_rn(a,b); }
__device__ __forceinline__ float fsub32(float a, float b){ return __fsub_rn(a,b); }

// ---- per-thread insertion top-20 on f32 (largest, ties keep lowest index) ----
__device__ __forceinline__ void insert_candidatef(float v, int j,
                                                  float (&best)[K], int (&bidx)[K]) {
  if (v > best[K-1]) {
    best[K-1] = v; bidx[K-1] = j;
    #pragma unroll
    for (int i = K-1; i >= 1; --i) {
      if (best[i] > best[i-1]) {
        float tv = best[i]; best[i] = best[i-1]; best[i-1] = tv;
        int   ti = bidx[i]; bidx[i] = bidx[i-1]; bidx[i-1] = ti;
      }
    }
  }
}

// ---- kNN on 3-D coords, numpy-f32-faithful (BIT-FROZEN) ----
__global__ __launch_bounds__(64) void knn_xyz_f32(const float* __restrict__ x,
                                                  int* __restrict__ idxo) {
  int row = blockIdx.x * 64 + threadIdx.x;   // grid = B*N/64
  int b = row >> 11, n = row & (N - 1);
  const float* xb = x + (size_t)b * N * 3;
  float xi0 = xb[(size_t)n*3], xi1 = xb[(size_t)n*3+1], xi2 = xb[(size_t)n*3+2];
  float xxi = fadd32(fadd32(fmul32(xi0,xi0), fmul32(xi1,xi1)), fmul32(xi2,xi2));
  float best[K]; int bidx[K];
  #pragma unroll
  for (int i = 0; i < K; ++i) { best[i] = -INFINITY; bidx[i] = 0; }
  for (int j = 0; j < N; ++j) {
    float a = xb[(size_t)j*3], c = xb[(size_t)j*3+1], d = xb[(size_t)j*3+2];
    float xxj   = fadd32(fadd32(fmul32(a,a), fmul32(c,c)), fmul32(d,d));
    float inner = fadd32(fadd32(fmul32(xi0,a), fmul32(xi1,c)), fmul32(xi2,d));
    float v = fsub32(fsub32(fmul32(2.f, inner), xxi), xxj);
    insert_candidatef(v, j, best, bidx);
  }
  int* o = idxo + (size_t)row * K;
  #pragma unroll
  for (int i = 0; i < K; ++i) o[i] = bidx[i];
}

// ---- x2 -> f32 copy + numpy pairwise(n=128) sum of squares (BIT-FROZEN) ----
__global__ __launch_bounds__(64) void xx2f_kernel(const double* __restrict__ x2d,
                                                  float* __restrict__ x2f,
                                                  float* __restrict__ xx2f) {
  int row = blockIdx.x * 64 + threadIdx.x;   // grid = B*N/64
  const double* src = x2d + (size_t)row * C2;
  float* dst = x2f + (size_t)row * C2;
  float sq[C2];
  #pragma unroll 8
  for (int c = 0; c < C2; ++c) {
    float v = (float)src[c];
    dst[c] = v;
    sq[c] = fmul32(v, v);
  }
  float r0=sq[0], r1=sq[1], r2=sq[2], r3=sq[3], r4=sq[4], r5=sq[5], r6=sq[6], r7=sq[7];
  #pragma unroll
  for (int i = 8; i < 128; i += 8) {
    r0 = fadd32(r0, sq[i+0]); r1 = fadd32(r1, sq[i+1]);
    r2 = fadd32(r2, sq[i+2]); r3 = fadd32(r3, sq[i+3]);
    r4 = fadd32(r4, sq[i+4]); r5 = fadd32(r5, sq[i+5]);
    r6 = fadd32(r6, sq[i+6]); r7 = fadd32(r7, sq[i+7]);
  }
  xx2f[row] = fadd32(fadd32(fadd32(r0,r1), fadd32(r2,r3)),
                     fadd32(fadd32(r4,r5), fadd32(r6,r7)));
}

// ---- all-batch neg-distance matrix, f32 sequential (BIT-FROZEN inner) ----
__global__ __launch_bounds__(256) void dist_f32_kernel(const float* __restrict__ x2f,
                                                       const float* __restrict__ xx2f,
                                                       float* __restrict__ dist) {
  int bz = blockIdx.z;
  const float* x2b  = x2f  + (size_t)bz * N * C2;
  const float* xx2b = xx2f + (size_t)bz * N;
  float* db = dist + (size_t)bz * N * N;
  int ti = blockIdx.y * 64;
  int tj = blockIdx.x * 64;
  int tid = threadIdx.x;
  int tr = tid >> 4, tc = tid & 15;
  __shared__ float A[64][9], Bm[64][9];
  float acc[4][4];
  #pragma unroll
  for (int u = 0; u < 4; ++u)
    #pragma unroll
    for (int v = 0; v < 4; ++v) acc[u][v] = 0.f;
  for (int c0 = 0; c0 < C2; c0 += 8) {
    for (int i = tid; i < 512; i += 256) {
      int r = i >> 3, c = i & 7;
      A[r][c]  = x2b[(size_t)(ti + r)*C2 + c0 + c];
      Bm[r][c] = x2b[(size_t)(tj + r)*C2 + c0 + c];
    }
    __syncthreads();
    #pragma unroll
    for (int c = 0; c < 8; ++c) {       // ascending c: exact sequential order
      float a[4], bv[4];
      #pragma unroll
      for (int u = 0; u < 4; ++u) a[u] = A[tr*4 + u][c];
      #pragma unroll
      for (int v = 0; v < 4; ++v) bv[v] = Bm[tc*4 + v][c];
      #pragma unroll
      for (int u = 0; u < 4; ++u)
        #pragma unroll
        for (int v = 0; v < 4; ++v)
          acc[u][v] = fadd32(acc[u][v], fmul32(a[u], bv[v]));
    }
    __syncthreads();
  }
  #pragma unroll
  for (int u = 0; u < 4; ++u) {
    int i = ti + tr*4 + u;
    float xxi = xx2b[i];
    #pragma unroll
    for (int v = 0; v < 4; ++v) {
      int j = tj + tc*4 + v;
      db[(size_t)i*N + j] = fsub32(fsub32(fmul32(2.f, acc[u][v]), xxi), xx2b[j]);
    }
  }
}

// ---- all-batch top-k from f32 distance rows (BIT-FROZEN) ----
__global__ __launch_bounds__(64) void knn_feat_f32(const float* __restrict__ dist,
                                                   int* __restrict__ idxo) {
  int row = blockIdx.x * 64 + threadIdx.x;   // grid = B*N/64
  const float* dr = dist + (size_t)row * N;
  float best[K]; int bidx[K];
  #pragma unroll
  for (int i = 0; i < K; ++i) { best[i] = -INFINITY; bidx[i] = 0; }
  for (int j = 0; j < N; ++j) insert_candidatef(dr[j], j, best, bidx);
  int* o = idxo + (size_t)row * K;
  #pragma unroll
  for (int i = 0; i < K; ++i) o[i] = bidx[i];
}

// ---- layer 1 (two-pass, f64): geometry + conv1 (BIT-FROZEN) ----
template<int PASS>
__global__ __launch_bounds__(64) void l1_kernel(
    const float* __restrict__ x, const float* __restrict__ nrm,
    const float* __restrict__ w1, const int* __restrict__ idx1,
    double* __restrict__ sS, double* __restrict__ sQ,
    const double* __restrict__ mid, const float* __restrict__ g1, const float* __restrict__ b1,
    double* __restrict__ x1d, float* __restrict__ out448,
    float* __restrict__ outR1, float* __restrict__ outR2) {
  int p = blockIdx.x;
  int tid = threadIdx.x;
  int b = p >> 11, n = p & (N - 1);
  __shared__ float  wl[C1 * 9];
  __shared__ double rotd[K][3];
  __shared__ double fld[K][9];
  for (int i = tid; i < C1 * 9; i += 64) wl[i] = w1[i];
  const float* xb = x + (size_t)b * N * 3;
  double nx = nrm[(size_t)p*3], ny = nrm[(size_t)p*3+1], nz = nrm[(size_t)p*3+2];
  double vx = ny, vy = -nx;
  double s = 1.0 / fmax(1.0 + nz, 1e-8);
  double vxy = vx * vy;
  double R1v[9];
  R1v[0] = 1.0 - s*(vy*vy); R1v[1] = s*vxy;           R1v[2] = vy;
  R1v[3] = s*vxy;           R1v[4] = 1.0 - s*(vx*vx); R1v[5] = -vx;
  R1v[6] = -vy;             R1v[7] = vx;              R1v[8] = 1.0 - s*(vx*vx + vy*vy);
  double xi0 = xb[(size_t)n*3], xi1 = xb[(size_t)n*3+1], xi2 = xb[(size_t)n*3+2];
  if (tid < K) {
    int j = idx1[(size_t)p*K + tid];
    double d0 = (double)xb[(size_t)j*3]   - xi0;
    double d1 = (double)xb[(size_t)j*3+1] - xi1;
    double d2 = (double)xb[(size_t)j*3+2] - xi2;
    rotd[tid][0] = R1v[0]*d0 + R1v[1]*d1 + R1v[2]*d2;
    rotd[tid][1] = R1v[3]*d0 + R1v[4]*d1 + R1v[5]*d2;
    rotd[tid][2] = R1v[6]*d0 + R1v[7]*d1 + R1v[8]*d2;
  }
  __syncthreads();
  double mx = 0.0, my = 0.0;
  #pragma unroll
  for (int k = 0; k < K; ++k) { mx += rotd[k][0]; my += rotd[k][1]; }
  mx /= 20.0; my /= 20.0;
  double r = sqrt(mx*mx + my*my);
  double ct = 1.0, st = 0.0;
  if (r > 0.0) { ct = mx / r; st = my / r; }   // cos/sin of atan2(my,mx)
  if (tid < K) {
    double r0 = rotd[tid][0], r1 = rotd[tid][1], r2 = rotd[tid][2];
    double a0 = ct*r0 + st*r1;
    double a1 = ct*r1 - st*r0;
    fld[tid][0] = a0;  fld[tid][1] = a1;   fld[tid][2] = r2;
    fld[tid][3] = a0;  fld[tid][4] = -a1;  fld[tid][5] = r2;   // xz-mirror
    fld[tid][6] = xi0; fld[tid][7] = xi1;  fld[tid][8] = xi2;  // x_rep
  }
  if (PASS == 0 && tid == 0) {
    float* o1 = outR1 + (size_t)p * 9;
    #pragma unroll
    for (int i = 0; i < 9; ++i) o1[i] = (float)R1v[i];
    float* o2 = outR2 + (size_t)p * 9;
    o2[0] = (float)ct;  o2[1] = (float)st; o2[2] = 0.f;
    o2[3] = (float)-st; o2[4] = (float)ct; o2[5] = 0.f;
    o2[6] = 0.f;        o2[7] = 0.f;       o2[8] = 1.f;
  }
  __syncthreads();
  int o = tid;
  if (PASS == 0) {
    double sum = 0., sq = 0.;
    #pragma unroll
    for (int k = 0; k < K; ++k) {
      double h = 0.;
      #pragma unroll
      for (int c = 0; c < 9; ++c) h = fma((double)wl[o*9 + c], fld[k][c], h);
      sum += h; sq += h*h;
    }
    int slice = p & (NSLICE - 1);
    atomicAdd(&sS[slice*C3 + o], sum);
    atomicAdd(&sQ[slice*C3 + o], sq);
  } else {
    double m = mid[o], is = mid[C3 + o];
    double g = g1[o], bb = b1[o];
    double mxv = -INFINITY;
    #pragma unroll
    for (int k = 0; k < K; ++k) {
      double h = 0.;
      #pragma unroll
      for (int c = 0; c < 9; ++c) h = fma((double)wl[o*9 + c], fld[k][c], h);
      double y = ((h - m) * is) * g + bb;
      y = y > 0.0 ? y : 0.2 * y;
      mxv = fmax(mxv, y);
    }
    x1d[(size_t)p*C1 + o] = mxv;
    out448[(size_t)p*448 + o] = (float)mxv;
  }
}

// ---- conv2 core: exact round-8 op sequence, 128 threads, NOUT=1 ----
__device__ __forceinline__ void conv2_core(const double* __restrict__ x1d,
                                           const int* __restrict__ idx,
                                           const float* __restrict__ w,
                                           int p, int tid, double (&acc)[K],
                                           double (&xiOut)[1]) {
  int b = p >> 11;
  __shared__ double difL[K][C1];
  __shared__ double xiL[C1];
  __shared__ int jidx[K];
  if (tid < K) jidx[tid] = idx[(size_t)p*K + tid];
  if (tid < C1) xiL[tid] = x1d[(size_t)p*C1 + tid];
  __syncthreads();
  #pragma unroll 1
  for (int i = tid; i < K*C1; i += 128) {
    int k = i >> 6, c = i & 63;
    difL[k][c] = x1d[((size_t)b*N + jidx[k])*C1 + c] - xiL[c];
  }
  __syncthreads();
  const float* wr = w + (size_t)tid * (2*C1);
  #pragma unroll
  for (int k = 0; k < K; ++k) acc[k] = 0.0;
  // phase 1: diff operand, c ascending per acc
  #pragma unroll
  for (int c0 = 0; c0 < C1; c0 += 16) {
    double wd[16];
    #pragma unroll
    for (int i = 0; i < 16; ++i) wd[i] = (double)wr[c0+i];
    #pragma unroll
    for (int k = 0; k < K; ++k) {
      #pragma unroll
      for (int i = 0; i < 16; ++i) acc[k] = fma(wd[i], difL[k][c0+i], acc[k]);
    }
  }
  // phase 2: x_rep operand, c ascending per acc
  #pragma unroll
  for (int c0 = 0; c0 < C1; c0 += 16) {
    double wd[16], xiv[16];
    #pragma unroll
    for (int i = 0; i < 16; ++i) { wd[i] = (double)wr[C1+c0+i]; xiv[i] = xiL[c0+i]; }
    #pragma unroll
    for (int k = 0; k < K; ++k) {
      #pragma unroll
      for (int i = 0; i < 16; ++i) acc[k] = fma(wd[i], xiv[i], acc[k]);
    }
  }
  xiOut[0] = 0.0;
}

// ---- conv2 pass0 (fast): conv once + stats + h2 store ----
__global__ __launch_bounds__(128, 1) void conv2_p0_store(
    const double* __restrict__ x1d, const int* __restrict__ idx,
    const float* __restrict__ w,
    double* __restrict__ sS, double* __restrict__ sQ,
    double* __restrict__ h2) {
  int p = blockIdx.x;
  int tid = threadIdx.x;
  double acc[K]; double dummy[1];
  conv2_core(x1d, idx, w, p, tid, acc, dummy);
  double sum = 0., sq = 0.;
  double* hb = h2 + (size_t)p * K * C2;
  #pragma unroll
  for (int k = 0; k < K; ++k) {
    sum += acc[k]; sq += acc[k]*acc[k];
    hb[k*C2 + tid] = acc[k];
  }
  int slice = p & (NSLICE - 1);
  atomicAdd(&sS[slice*C3 + tid], sum);
  atomicAdd(&sQ[slice*C3 + tid], sq);
}

// ---- conv2 pass1 (fast): load h2 + BN + max ----
__global__ __launch_bounds__(128, 1) void conv2_p1_load(
    const double* __restrict__ h2, const double* __restrict__ mid,
    const float* __restrict__ gam, const float* __restrict__ bet,
    double* __restrict__ x2d, float* __restrict__ out448) {
  int p = blockIdx.x;
  int tid = threadIdx.x;
  double m = mid[tid], is = mid[C3 + tid];
  double g = gam[tid], bb = bet[tid];
  const double* hb = h2 + (size_t)p * K * C2;
  double mxv = -INFINITY;
  #pragma unroll
  for (int k = 0; k < K; ++k) {
    double y = ((hb[k*C2 + tid] - m) * is) * g + bb;
    y = y > 0.0 ? y : 0.2 * y;
    mxv = fmax(mxv, y);
  }
  x2d[(size_t)p*C2 + tid] = mxv;
  out448[(size_t)p*448 + C1 + tid] = (float)mxv;
}

// ---- conv2 fallback (recompute, round-8) ----
template<int PASS>
__global__ __launch_bounds__(128, 1) void conv2_full(
    const double* __restrict__ x1d, const int* __restrict__ idx,
    const float* __restrict__ w,
    double* __restrict__ sS, double* __restrict__ sQ,
    const double* __restrict__ mid, const float* __restrict__ gam, const float* __restrict__ bet,
    double* __restrict__ x2d, float* __restrict__ out448) {
  int p = blockIdx.x;
  int tid = threadIdx.x;
  double acc[K]; double dummy[1];
  conv2_core(x1d, idx, w, p, tid, acc, dummy);
  if (PASS == 0) {
    double sum = 0., sq = 0.;
    #pragma unroll
    for (int k = 0; k < K; ++k) { sum += acc[k]; sq += acc[k]*acc[k]; }
    int slice = p & (NSLICE - 1);
    atomicAdd(&sS[slice*C3 + tid], sum);
    atomicAdd(&sQ[slice*C3 + tid], sq);
  } else {
    double m = mid[tid], is = mid[C3 + tid];
    double g = gam[tid], bb = bet[tid];
    double mxv = -INFINITY;
    #pragma unroll
    for (int k = 0; k < K; ++k) {
      double y = ((acc[k] - m) * is) * g + bb;
      y = y > 0.0 ? y : 0.2 * y;
      mxv = fmax(mxv, y);
    }
    x2d[(size_t)p*C2 + tid] = mxv;
    out448[(size_t)p*448 + C1 + tid] = (float)mxv;
  }
}

// ---- conv3 pass0 (fast): 128 threads, NOUT=2 (o = tid, tid+128), conv once
// + stats + h3 store. Per-acc fmaf order = round-8 (c ascending). ----
__global__ __launch_bounds__(128, 1) void conv3_p0_store(
    const float* __restrict__ x2f, const int* __restrict__ idx,
    const float* __restrict__ w,
    double* __restrict__ sS, double* __restrict__ sQ,
    float* __restrict__ h3) {
  int p = blockIdx.x;
  int tid = threadIdx.x;
  int b = p >> 11;
  __shared__ float xjL[K][C2];
  __shared__ float xiL[C2];
  __shared__ int jidx[K];
  if (tid < K) jidx[tid] = idx[(size_t)p*K + tid];
  xiL[tid] = x2f[(size_t)p*C2 + tid];
  __syncthreads();
  #pragma unroll 1
  for (int i = tid; i < K*C2; i += 128) {
    int k = i >> 7, c = i & 127;
    xjL[k][c] = x2f[((size_t)b*N + jidx[k])*C2 + c];
  }
  __syncthreads();
  const float* wr0 = w + (size_t)tid * (2*C2);
  const float* wr1 = w + (size_t)(tid + 128) * (2*C2);
  float base0 = 0.f, base1 = 0.f;
  #pragma unroll 1
  for (int c0 = 0; c0 < C2; c0 += 8) {
    #pragma unroll
    for (int i = 0; i < 8; ++i) {
      float xv = xiL[c0+i];
      base0 = fmaf(wr0[C2+c0+i] - wr0[c0+i], xv, base0);
      base1 = fmaf(wr1[C2+c0+i] - wr1[c0+i], xv, base1);
    }
  }
  float acc0[K], acc1[K];
  #pragma unroll
  for (int k = 0; k < K; ++k) { acc0[k] = base0; acc1[k] = base1; }
  #pragma unroll 1
  for (int c0 = 0; c0 < C2; c0 += 8) {
    float w0[8], w1v[8];
    #pragma unroll
    for (int i = 0; i < 8; ++i) { w0[i] = wr0[c0+i]; w1v[i] = wr1[c0+i]; }
    #pragma unroll
    for (int k = 0; k < K; ++k) {
      float xv[8];
      #pragma unroll
      for (int i = 0; i < 8; ++i) xv[i] = xjL[k][c0+i];
      #pragma unroll
      for (int i = 0; i < 8; ++i) acc0[k] = fmaf(w0[i], xv[i], acc0[k]);
      #pragma unroll
      for (int i = 0; i < 8; ++i) acc1[k] = fmaf(w1v[i], xv[i], acc1[k]);
    }
  }
  double s0 = 0., q0 = 0., s1 = 0., q1 = 0.;
  float* hb = h3 + (size_t)p * K * C3;
  #pragma unroll
  for (int k = 0; k < K; ++k) {
    double h0 = (double)acc0[k]; s0 += h0; q0 += h0*h0;
    double h1 = (double)acc1[k]; s1 += h1; q1 += h1*h1;
    hb[k*C3 + tid] = acc0[k];
    hb[k*C3 + tid + 128] = acc1[k];
  }
  int slice = p & (NSLICE - 1);
  atomicAdd(&sS[slice*C3 + tid], s0);
  atomicAdd(&sQ[slice*C3 + tid], q0);
  atomicAdd(&sS[slice*C3 + tid + 128], s1);
  atomicAdd(&sQ[slice*C3 + tid + 128], q1);
}

// ---- conv3 pass1 (fast): load h3 + BN + max ----
__global__ __launch_bounds__(256, 1) void conv3_p1_load(
    const float* __restrict__ h3, const double* __restrict__ mid,
    const float* __restrict__ gam, const float* __restrict__ bet,
    float* __restrict__ out448) {
  int p = blockIdx.x;
  int o = threadIdx.x;
  float m = (float)mid[o], is = (float)mid[C3 + o];
  float g = gam[o], bb = bet[o];
  const float* hb = h3 + (size_t)p * K * C3;
  float mxv = -INFINITY;
  #pragma unroll
  for (int k = 0; k < K; ++k) {
    float y = (hb[k*C3 + o] - m) * is * g + bb;
    y = y > 0.f ? y : 0.2f * y;
    mxv = fmaxf(mxv, y);
  }
  out448[(size_t)p*448 + C1 + C2 + o] = mxv;
}

// ---- conv3 fallback (recompute, round-8, 256 threads NOUT=1) ----
template<int PASS>
__global__ __launch_bounds__(256, 1) void conv3_full(
    const float* __restrict__ x2f, const int* __restrict__ idx,
    const float* __restrict__ w,
    double* __restrict__ sS, double* __restrict__ sQ,
    const double* __restrict__ mid, const float* __restrict__ gam, const float* __restrict__ bet,
    float* __restrict__ out448) {
  int p = blockIdx.x;
  int tid = threadIdx.x;
  int b = p >> 11;
  __shared__ float xjL[K][C2];
  __shared__ float xiL[C2];
  __shared__ int jidx[K];
  if (tid < K) jidx[tid] = idx[(size_t)p*K + tid];
  if (tid < C2) xiL[tid] = x2f[(size_t)p*C2 + tid];
  __syncthreads();
  #pragma unroll 1
  for (int i = tid; i < K*C2; i += 256) {
    int k = i >> 7, c = i & 127;
    xjL[k][c] = x2f[((size_t)b*N + jidx[k])*C2 + c];
  }
  __syncthreads();
  const float* wr = w + (size_t)tid * (2*C2);
  float base = 0.f;
  #pragma unroll
  for (int c0 = 0; c0 < C2; c0 += 32) {
    #pragma unroll
    for (int i = 0; i < 32; ++i)
      base = fmaf(wr[C2+c0+i] - wr[c0+i], xiL[c0+i], base);
  }
  float acc[K];
  #pragma unroll
  for (int k = 0; k < K; ++k) acc[k] = base;
  #pragma unroll
  for (int c0 = 0; c0 < C2; c0 += 32) {
    float wd[32];
    #pragma unroll
    for (int i = 0; i < 32; ++i) wd[i] = wr[c0+i];
    #pragma unroll
    for (int k = 0; k < K; ++k) {
      #pragma unroll
      for (int i = 0; i < 32; ++i) acc[k] = fmaf(wd[i], xjL[k][c0+i], acc[k]);
    }
  }
  if (PASS == 0) {
    double sum = 0., sq = 0.;
    #pragma unroll
    for (int k = 0; k < K; ++k) {
      double h = (double)acc[k];
      sum += h; sq += h*h;
    }
    int slice = p & (NSLICE - 1);
    atomicAdd(&sS[slice*C3 + tid], sum);
    atomicAdd(&sQ[slice*C3 + tid], sq);
  } else {
    float m = (float)mid[tid], is = (float)mid[C3 + tid];
    float g = gam[tid], bb = bet[tid];
    float mxv = -INFINITY;
    #pragma unroll
    for (int k = 0; k < K; ++k) {
      float y = (acc[k] - m) * is * g + bb;
      y = y > 0.f ? y : 0.2f * y;
      mxv = fmaxf(mxv, y);
    }
    out448[(size_t)p*448 + C1 + C2 + tid] = mxv;
  }
}

// ---- finalize BN stats (f64) ----
__global__ void finalize_stats(const double* __restrict__ sS, const double* __restrict__ sQ,
                               double* __restrict__ mid, int C) {
  int o = threadIdx.x;
  if (o >= C) return;
  double s = 0., q = 0.;
  for (int i = 0; i < NSLICE; ++i) { s += sS[i*C3 + o]; q += sQ[i*C3 + o]; }
  double m = s / COUNT;
  double v = q / COUNT - m*m;
  mid[o] = m;
  mid[C3 + o] = 1.0 / sqrt(v + BNEPS);
}

} // namespace

extern "C" void kernel_launch(void* const* d_in, const int* in_sizes, int n_in,
                              void* d_out, int out_size, void* d_ws, size_t ws_size,
                              hipStream_t stream) {
  (void)in_sizes; (void)n_in; (void)out_size;
  const float* x   = (const float*)d_in[0];
  const float* nrm = (const float*)d_in[1];
  const float* w1  = (const float*)d_in[2];
  const float* g1  = (const float*)d_in[3];
  const float* b1  = (const float*)d_in[4];
  const float* w2  = (const float*)d_in[5];
  const float* g2  = (const float*)d_in[6];
  const float* b2  = (const float*)d_in[7];
  const float* w3  = (const float*)d_in[8];
  const float* g3  = (const float*)d_in[9];
  const float* b3  = (const float*)d_in[10];
  float* out = (float*)d_out;
  char*  ws  = (char*)d_ws;

  int*    idx1 = (int*)(ws + OFF_IDX1);
  int*    idx2 = (int*)(ws + OFF_IDX2);
  double* x1d  = (double*)(ws + OFF_X1D);
  double* x2d  = (double*)(ws + OFF_X2D);
  double* sS   = (double*)(ws + OFF_STATS);
  double* sQ   = sS + (size_t)NSLICE * C3;
  double* mid  = (double*)(ws + OFF_MI);
  float*  x2f  = (float*)(ws + OFF_X2F);
  float*  xx2f = (float*)(ws + OFF_XX2F);
  char*   big  = ws + OFF_BIG;
  double* h2   = (double*)big;     // fast path; dead before dist written
  float*  h3   = (float*)big;      // fast path; written after dist dead
  float*  dist = (float*)big;      // always

  const bool fast = ws_size >= NEED_FAST;

  float* outR1 = out + (size_t)B * N * 448;
  float* outR2 = outR1 + (size_t)B * N * 9;

  // kNN1 — numpy-f32-faithful formula
  knn_xyz_f32<<<B*N/64, 64, 0, stream>>>(x, idx1);

  // layer 1 (f64 two-pass)
  hipMemsetAsync(sS, 0, (size_t)2*NSLICE*C3*sizeof(double), stream);
  l1_kernel<0><<<B*N, 64, 0, stream>>>(x, nrm, w1, idx1, sS, sQ, nullptr, nullptr, nullptr,
                                       nullptr, nullptr, outR1, outR2);
  finalize_stats<<<1, C3, 0, stream>>>(sS, sQ, mid, C1);
  l1_kernel<1><<<B*N, 64, 0, stream>>>(x, nrm, w1, idx1, nullptr, nullptr, mid, g1, b1,
                                       x1d, out, outR1, outR2);

  // layer 2 (f64, bit-exact op order; store-h2 if workspace allows)
  hipMemsetAsync(sS, 0, (size_t)2*NSLICE*C3*sizeof(double), stream);
  if (fast) {
    conv2_p0_store<<<B*N, 128, 0, stream>>>(x1d, idx1, w2, sS, sQ, h2);
    finalize_stats<<<1, C3, 0, stream>>>(sS, sQ, mid, C2);
    conv2_p1_load<<<B*N, 128, 0, stream>>>(h2, mid, g2, b2, x2d, out);
  } else {
    conv2_full<0><<<B*N, 128, 0, stream>>>(x1d, idx1, w2, sS, sQ, nullptr, nullptr, nullptr,
                                           nullptr, nullptr);
    finalize_stats<<<1, C3, 0, stream>>>(sS, sQ, mid, C2);
    conv2_full<1><<<B*N, 128, 0, stream>>>(x1d, idx1, w2, nullptr, nullptr, mid, g2, b2,
                                           x2d, out);
  }

  // kNN2 — numpy-f32-faithful, all batches fused (dist overwrites dead h2)
  xx2f_kernel<<<B*N/64, 64, 0, stream>>>(x2d, x2f, xx2f);
  dist_f32_kernel<<<dim3(N/64, N/64, B), 256, 0, stream>>>(x2f, xx2f, dist);
  knn_feat_f32<<<B*N/64, 64, 0, stream>>>(dist, idx2);

  // layer 3 (f32 value path; store-h3 if workspace allows; h3 overwrites dead dist)
  hipMemsetAsync(sS, 0, (size_t)2*NSLICE*C3*sizeof(double), stream);
  if (fast) {
    conv3_p0_store<<<B*N, 128, 0, stream>>>(x2f, idx2, w3, sS, sQ, h3);
    finalize_stats<<<1, C3, 0, stream>>>(sS, sQ, mid, C3);
    conv3_p1_load<<<B*N, 256, 0, stream>>>(h3, mid, g3, b3, out);
  } else {
    conv3_full<0><<<B*N, 256, 0, stream>>>(x2f, idx2, w3, sS, sQ, nullptr, nullptr, nullptr,
                                           nullptr);
    finalize_stats<<<1, C3, 0, stream>>>(sS, sQ, mid, C3);
    conv3_full<1><<<B*N, 256, 0, stream>>>(x2f, idx2, w3, nullptr, nullptr, mid, g3, b3,
                                           out);
  }
}

// Round 11
// 3187.140 us; speedup vs baseline: 1.7168x; 1.0775x over previous
//
#include <hip/hip_runtime.h>
#include <hip/hip_bf16.h>
#include <math.h>

namespace {

constexpr int B  = 8;
constexpr int N  = 2048;     // power of two: n = p & 2047, b = p >> 11
constexpr int K  = 20;
constexpr int C1 = 64, C2 = 128, C3 = 256;
constexpr int NSLICE = 64;
constexpr double COUNT = 327680.0;   // B*N*K
constexpr double BNEPS = 1e-5;

// ---- workspace layout (bytes) ----
constexpr size_t OFF_IDX1  = 0;                                  // B*N*K int
constexpr size_t OFF_IDX2  = OFF_IDX1 + (size_t)B*N*K*4;         // B*N*K int
constexpr size_t OFF_X1D   = OFF_IDX2 + (size_t)B*N*K*4;         // B*N*C1 f64
constexpr size_t OFF_X2D   = OFF_X1D  + (size_t)B*N*C1*8;        // B*N*C2 f64
constexpr size_t OFF_STATS = OFF_X2D  + (size_t)B*N*C2*8;        // 2*NSLICE*C3 f64
constexpr size_t OFF_MI    = OFF_STATS+ (size_t)2*NSLICE*C3*8;   // 2*C3 f64
constexpr size_t OFF_X2F   = OFF_MI   + 4096;                    // B*N*C2 f32
constexpr size_t OFF_XX2F  = OFF_X2F  + (size_t)B*N*C2*4;        // B*N f32
constexpr size_t OFF_BIG   = OFF_XX2F + (size_t)B*N*4;           // shared big region
// big region, strictly sequential lifetimes:
//   dist f32 (134.2 MB)  ->  h3 bf16 (83.9 MB)
// footprint = OFF_BIG + 134.2 MB — identical to round-7/8/10 (proven to fit).

// ---- strict-rounding f32 helpers (block FMA contraction / reassociation) ----
__device__ __forceinline__ float fmul32(float a, float b){ return __fmul_rn(a,b); }
__device__ __forceinline__ float fadd32(float a, float b){ return __fadd_rn(a,b); }
__device__ __forceinline__ float fsub32(float a, float b){ return __fsub_rn(a,b); }

// ---- per-thread insertion top-20 on f32 (largest, ties keep lowest index) ----
__device__ __forceinline__ void insert_candidatef(float v, int j,
                                                  float (&best)[K], int (&bidx)[K]) {
  if (v > best[K-1]) {
    best[K-1] = v; bidx[K-1] = j;
    #pragma unroll
    for (int i = K-1; i >= 1; --i) {
      if (best[i] > best[i-1]) {
        float tv = best[i]; best[i] = best[i-1]; best[i-1] = tv;
        int   ti = bidx[i]; bidx[i] = bidx[i-1]; bidx[i-1] = ti;
      }
    }
  }
}

// ---- kNN on 3-D coords, numpy-f32-faithful (BIT-FROZEN) ----
__global__ __launch_bounds__(64) void knn_xyz_f32(const float* __restrict__ x,
                                                  int* __restrict__ idxo) {
  int row = blockIdx.x * 64 + threadIdx.x;   // grid = B*N/64
  int b = row >> 11, n = row & (N - 1);
  const float* xb = x + (size_t)b * N * 3;
  float xi0 = xb[(size_t)n*3], xi1 = xb[(size_t)n*3+1], xi2 = xb[(size_t)n*3+2];
  float xxi = fadd32(fadd32(fmul32(xi0,xi0), fmul32(xi1,xi1)), fmul32(xi2,xi2));
  float best[K]; int bidx[K];
  #pragma unroll
  for (int i = 0; i < K; ++i) { best[i] = -INFINITY; bidx[i] = 0; }
  for (int j = 0; j < N; ++j) {
    float a = xb[(size_t)j*3], c = xb[(size_t)j*3+1], d = xb[(size_t)j*3+2];
    float xxj   = fadd32(fadd32(fmul32(a,a), fmul32(c,c)), fmul32(d,d));
    float inner = fadd32(fadd32(fmul32(xi0,a), fmul32(xi1,c)), fmul32(xi2,d));
    float v = fsub32(fsub32(fmul32(2.f, inner), xxi), xxj);
    insert_candidatef(v, j, best, bidx);
  }
  int* o = idxo + (size_t)row * K;
  #pragma unroll
  for (int i = 0; i < K; ++i) o[i] = bidx[i];
}

// ---- x2 -> f32 copy + numpy pairwise(n=128) sum of squares (BIT-FROZEN) ----
__global__ __launch_bounds__(64) void xx2f_kernel(const double* __restrict__ x2d,
                                                  float* __restrict__ x2f,
                                                  float* __restrict__ xx2f) {
  int row = blockIdx.x * 64 + threadIdx.x;   // grid = B*N/64
  const double* src = x2d + (size_t)row * C2;
  float* dst = x2f + (size_t)row * C2;
  float sq[C2];
  #pragma unroll 8
  for (int c = 0; c < C2; ++c) {
    float v = (float)src[c];
    dst[c] = v;
    sq[c] = fmul32(v, v);
  }
  float r0=sq[0], r1=sq[1], r2=sq[2], r3=sq[3], r4=sq[4], r5=sq[5], r6=sq[6], r7=sq[7];
  #pragma unroll
  for (int i = 8; i < 128; i += 8) {
    r0 = fadd32(r0, sq[i+0]); r1 = fadd32(r1, sq[i+1]);
    r2 = fadd32(r2, sq[i+2]); r3 = fadd32(r3, sq[i+3]);
    r4 = fadd32(r4, sq[i+4]); r5 = fadd32(r5, sq[i+5]);
    r6 = fadd32(r6, sq[i+6]); r7 = fadd32(r7, sq[i+7]);
  }
  xx2f[row] = fadd32(fadd32(fadd32(r0,r1), fadd32(r2,r3)),
                     fadd32(fadd32(r4,r5), fadd32(r6,r7)));
}

// ---- all-batch neg-distance matrix, f32 sequential (BIT-FROZEN inner) ----
__global__ __launch_bounds__(256) void dist_f32_kernel(const float* __restrict__ x2f,
                                                       const float* __restrict__ xx2f,
                                                       float* __restrict__ dist) {
  int bz = blockIdx.z;
  const float* x2b  = x2f  + (size_t)bz * N * C2;
  const float* xx2b = xx2f + (size_t)bz * N;
  float* db = dist + (size_t)bz * N * N;
  int ti = blockIdx.y * 64;
  int tj = blockIdx.x * 64;
  int tid = threadIdx.x;
  int tr = tid >> 4, tc = tid & 15;
  __shared__ float A[64][9], Bm[64][9];
  float acc[4][4];
  #pragma unroll
  for (int u = 0; u < 4; ++u)
    #pragma unroll
    for (int v = 0; v < 4; ++v) acc[u][v] = 0.f;
  for (int c0 = 0; c0 < C2; c0 += 8) {
    for (int i = tid; i < 512; i += 256) {
      int r = i >> 3, c = i & 7;
      A[r][c]  = x2b[(size_t)(ti + r)*C2 + c0 + c];
      Bm[r][c] = x2b[(size_t)(tj + r)*C2 + c0 + c];
    }
    __syncthreads();
    #pragma unroll
    for (int c = 0; c < 8; ++c) {       // ascending c: exact sequential order
      float a[4], bv[4];
      #pragma unroll
      for (int u = 0; u < 4; ++u) a[u] = A[tr*4 + u][c];
      #pragma unroll
      for (int v = 0; v < 4; ++v) bv[v] = Bm[tc*4 + v][c];
      #pragma unroll
      for (int u = 0; u < 4; ++u)
        #pragma unroll
        for (int v = 0; v < 4; ++v)
          acc[u][v] = fadd32(acc[u][v], fmul32(a[u], bv[v]));
    }
    __syncthreads();
  }
  #pragma unroll
  for (int u = 0; u < 4; ++u) {
    int i = ti + tr*4 + u;
    float xxi = xx2b[i];
    #pragma unroll
    for (int v = 0; v < 4; ++v) {
      int j = tj + tc*4 + v;
      db[(size_t)i*N + j] = fsub32(fsub32(fmul32(2.f, acc[u][v]), xxi), xx2b[j]);
    }
  }
}

// ---- wave-parallel top-20 on frozen dist values (coalesced reads).
// Comparator identical to insertion version: value desc, ties -> smaller index.
__global__ __launch_bounds__(256) void knn_feat_wave(const float* __restrict__ dist,
                                                     int* __restrict__ idxo) {
  int row  = blockIdx.x * 4 + (threadIdx.x >> 6);   // grid = B*N/4
  int lane = threadIdx.x & 63;
  const float* dr = dist + (size_t)row * N;
  float vals[32];
  #pragma unroll
  for (int t = 0; t < 32; ++t) vals[t] = dr[lane + (t << 6)];   // coalesced
  int* out = idxo + (size_t)row * K;
  for (int sel = 0; sel < K; ++sel) {
    float best = -INFINITY; int bt = 0;
    #pragma unroll
    for (int t = 0; t < 32; ++t)
      if (vals[t] > best) { best = vals[t]; bt = t; }   // local ties -> smaller t (smaller idx)
    int bcol = lane + (bt << 6);
    #pragma unroll
    for (int off = 32; off >= 1; off >>= 1) {
      float ov = __shfl_xor(best, off, 64);
      int   oc = __shfl_xor(bcol, off, 64);
      if (ov > best || (ov == best && oc < bcol)) { best = ov; bcol = oc; }
    }
    if (lane == 0) out[sel] = bcol;
    int kill = ((bcol & 63) == lane) ? (bcol >> 6) : 32;
    #pragma unroll
    for (int t = 0; t < 32; ++t) if (t == kill) vals[t] = -INFINITY;
  }
}

// ---- layer 1 (two-pass, f64): geometry + conv1 (BIT-FROZEN) ----
template<int PASS>
__global__ __launch_bounds__(64) void l1_kernel(
    const float* __restrict__ x, const float* __restrict__ nrm,
    const float* __restrict__ w1, const int* __restrict__ idx1,
    double* __restrict__ sS, double* __restrict__ sQ,
    const double* __restrict__ mid, const float* __restrict__ g1, const float* __restrict__ b1,
    double* __restrict__ x1d, float* __restrict__ out448,
    float* __restrict__ outR1, float* __restrict__ outR2) {
  int p = blockIdx.x;
  int tid = threadIdx.x;
  int b = p >> 11, n = p & (N - 1);
  __shared__ float  wl[C1 * 9];
  __shared__ double rotd[K][3];
  __shared__ double fld[K][9];
  for (int i = tid; i < C1 * 9; i += 64) wl[i] = w1[i];
  const float* xb = x + (size_t)b * N * 3;
  double nx = nrm[(size_t)p*3], ny = nrm[(size_t)p*3+1], nz = nrm[(size_t)p*3+2];
  double vx = ny, vy = -nx;
  double s = 1.0 / fmax(1.0 + nz, 1e-8);
  double vxy = vx * vy;
  double R1v[9];
  R1v[0] = 1.0 - s*(vy*vy); R1v[1] = s*vxy;           R1v[2] = vy;
  R1v[3] = s*vxy;           R1v[4] = 1.0 - s*(vx*vx); R1v[5] = -vx;
  R1v[6] = -vy;             R1v[7] = vx;              R1v[8] = 1.0 - s*(vx*vx + vy*vy);
  double xi0 = xb[(size_t)n*3], xi1 = xb[(size_t)n*3+1], xi2 = xb[(size_t)n*3+2];
  if (tid < K) {
    int j = idx1[(size_t)p*K + tid];
    double d0 = (double)xb[(size_t)j*3]   - xi0;
    double d1 = (double)xb[(size_t)j*3+1] - xi1;
    double d2 = (double)xb[(size_t)j*3+2] - xi2;
    rotd[tid][0] = R1v[0]*d0 + R1v[1]*d1 + R1v[2]*d2;
    rotd[tid][1] = R1v[3]*d0 + R1v[4]*d1 + R1v[5]*d2;
    rotd[tid][2] = R1v[6]*d0 + R1v[7]*d1 + R1v[8]*d2;
  }
  __syncthreads();
  double mx = 0.0, my = 0.0;
  #pragma unroll
  for (int k = 0; k < K; ++k) { mx += rotd[k][0]; my += rotd[k][1]; }
  mx /= 20.0; my /= 20.0;
  double r = sqrt(mx*mx + my*my);
  double ct = 1.0, st = 0.0;
  if (r > 0.0) { ct = mx / r; st = my / r; }   // cos/sin of atan2(my,mx)
  if (tid < K) {
    double r0 = rotd[tid][0], r1 = rotd[tid][1], r2 = rotd[tid][2];
    double a0 = ct*r0 + st*r1;
    double a1 = ct*r1 - st*r0;
    fld[tid][0] = a0;  fld[tid][1] = a1;   fld[tid][2] = r2;
    fld[tid][3] = a0;  fld[tid][4] = -a1;  fld[tid][5] = r2;   // xz-mirror
    fld[tid][6] = xi0; fld[tid][7] = xi1;  fld[tid][8] = xi2;  // x_rep
  }
  if (PASS == 0 && tid == 0) {
    float* o1 = outR1 + (size_t)p * 9;
    #pragma unroll
    for (int i = 0; i < 9; ++i) o1[i] = (float)R1v[i];
    float* o2 = outR2 + (size_t)p * 9;
    o2[0] = (float)ct;  o2[1] = (float)st; o2[2] = 0.f;
    o2[3] = (float)-st; o2[4] = (float)ct; o2[5] = 0.f;
    o2[6] = 0.f;        o2[7] = 0.f;       o2[8] = 1.f;
  }
  __syncthreads();
  int o = tid;
  if (PASS == 0) {
    double sum = 0., sq = 0.;
    #pragma unroll
    for (int k = 0; k < K; ++k) {
      double h = 0.;
      #pragma unroll
      for (int c = 0; c < 9; ++c) h = fma((double)wl[o*9 + c], fld[k][c], h);
      sum += h; sq += h*h;
    }
    int slice = p & (NSLICE - 1);
    atomicAdd(&sS[slice*C3 + o], sum);
    atomicAdd(&sQ[slice*C3 + o], sq);
  } else {
    double m = mid[o], is = mid[C3 + o];
    double g = g1[o], bb = b1[o];
    double mxv = -INFINITY;
    #pragma unroll
    for (int k = 0; k < K; ++k) {
      double h = 0.;
      #pragma unroll
      for (int c = 0; c < 9; ++c) h = fma((double)wl[o*9 + c], fld[k][c], h);
      double y = ((h - m) * is) * g + bb;
      y = y > 0.0 ? y : 0.2 * y;
      mxv = fmax(mxv, y);
    }
    x1d[(size_t)p*C1 + o] = mxv;
    out448[(size_t)p*448 + o] = (float)mxv;
  }
}

// ---- conv2 core: exact round-8 op sequence, 128 threads, NOUT=1 (BIT-FROZEN) ----
__device__ __forceinline__ void conv2_core(const double* __restrict__ x1d,
                                           const int* __restrict__ idx,
                                           const float* __restrict__ w,
                                           int p, int tid, double (&acc)[K]) {
  int b = p >> 11;
  __shared__ double difL[K][C1];
  __shared__ double xiL[C1];
  __shared__ int jidx[K];
  if (tid < K) jidx[tid] = idx[(size_t)p*K + tid];
  if (tid < C1) xiL[tid] = x1d[(size_t)p*C1 + tid];
  __syncthreads();
  #pragma unroll 1
  for (int i = tid; i < K*C1; i += 128) {
    int k = i >> 6, c = i & 63;
    difL[k][c] = x1d[((size_t)b*N + jidx[k])*C1 + c] - xiL[c];
  }
  __syncthreads();
  const float* wr = w + (size_t)tid * (2*C1);
  #pragma unroll
  for (int k = 0; k < K; ++k) acc[k] = 0.0;
  // phase 1: diff operand, c ascending per acc
  #pragma unroll
  for (int c0 = 0; c0 < C1; c0 += 16) {
    double wd[16];
    #pragma unroll
    for (int i = 0; i < 16; ++i) wd[i] = (double)wr[c0+i];
    #pragma unroll
    for (int k = 0; k < K; ++k) {
      #pragma unroll
      for (int i = 0; i < 16; ++i) acc[k] = fma(wd[i], difL[k][c0+i], acc[k]);
    }
  }
  // phase 2: x_rep operand, c ascending per acc
  #pragma unroll
  for (int c0 = 0; c0 < C1; c0 += 16) {
    double wd[16], xiv[16];
    #pragma unroll
    for (int i = 0; i < 16; ++i) { wd[i] = (double)wr[C1+c0+i]; xiv[i] = xiL[c0+i]; }
    #pragma unroll
    for (int k = 0; k < K; ++k) {
      #pragma unroll
      for (int i = 0; i < 16; ++i) acc[k] = fma(wd[i], xiv[i], acc[k]);
    }
  }
}

// ---- conv2 (two-pass recompute, round-8 proven) ----
template<int PASS>
__global__ __launch_bounds__(128, 1) void conv2_full(
    const double* __restrict__ x1d, const int* __restrict__ idx,
    const float* __restrict__ w,
    double* __restrict__ sS, double* __restrict__ sQ,
    const double* __restrict__ mid, const float* __restrict__ gam, const float* __restrict__ bet,
    double* __restrict__ x2d, float* __restrict__ out448) {
  int p = blockIdx.x;
  int tid = threadIdx.x;
  double acc[K];
  conv2_core(x1d, idx, w, p, tid, acc);
  if (PASS == 0) {
    double sum = 0., sq = 0.;
    #pragma unroll
    for (int k = 0; k < K; ++k) { sum += acc[k]; sq += acc[k]*acc[k]; }
    int slice = p & (NSLICE - 1);
    atomicAdd(&sS[slice*C3 + tid], sum);
    atomicAdd(&sQ[slice*C3 + tid], sq);
  } else {
    double m = mid[tid], is = mid[C3 + tid];
    double g = gam[tid], bb = bet[tid];
    double mxv = -INFINITY;
    #pragma unroll
    for (int k = 0; k < K; ++k) {
      double y = ((acc[k] - m) * is) * g + bb;
      y = y > 0.0 ? y : 0.2 * y;
      mxv = fmax(mxv, y);
    }
    x2d[(size_t)p*C2 + tid] = mxv;
    out448[(size_t)p*448 + C1 + tid] = (float)mxv;
  }
}

// ---- conv3 pass0: conv ONCE (NOUT=2 @128 threads, reg budget 256) + stats
// + h3 store as bf16. Per-acc fmaf order = round-8/10 (c ascending). ----
__global__ __launch_bounds__(128, 1) void conv3_p0_store(
    const float* __restrict__ x2f, const int* __restrict__ idx,
    const float* __restrict__ w,
    double* __restrict__ sS, double* __restrict__ sQ,
    __hip_bfloat16* __restrict__ h3) {
  int p = blockIdx.x;
  int tid = threadIdx.x;
  int b = p >> 11;
  __shared__ float xjL[K][C2];
  __shared__ float xiL[C2];
  __shared__ int jidx[K];
  if (tid < K) jidx[tid] = idx[(size_t)p*K + tid];
  xiL[tid] = x2f[(size_t)p*C2 + tid];
  __syncthreads();
  #pragma unroll 1
  for (int i = tid; i < K*C2; i += 128) {
    int k = i >> 7, c = i & 127;
    xjL[k][c] = x2f[((size_t)b*N + jidx[k])*C2 + c];
  }
  __syncthreads();
  const float* wr0 = w + (size_t)tid * (2*C2);
  const float* wr1 = w + (size_t)(tid + 128) * (2*C2);
  float base0 = 0.f, base1 = 0.f;
  #pragma unroll 1
  for (int c0 = 0; c0 < C2; c0 += 8) {
    #pragma unroll
    for (int i = 0; i < 8; ++i) {
      float xv = xiL[c0+i];
      base0 = fmaf(wr0[C2+c0+i] - wr0[c0+i], xv, base0);
      base1 = fmaf(wr1[C2+c0+i] - wr1[c0+i], xv, base1);
    }
  }
  float acc0[K], acc1[K];
  #pragma unroll
  for (int k = 0; k < K; ++k) { acc0[k] = base0; acc1[k] = base1; }
  #pragma unroll 1
  for (int c0 = 0; c0 < C2; c0 += 8) {
    float w0[8], w1v[8];
    #pragma unroll
    for (int i = 0; i < 8; ++i) { w0[i] = wr0[c0+i]; w1v[i] = wr1[c0+i]; }
    #pragma unroll
    for (int k = 0; k < K; ++k) {
      float xv[8];
      #pragma unroll
      for (int i = 0; i < 8; ++i) xv[i] = xjL[k][c0+i];
      #pragma unroll
      for (int i = 0; i < 8; ++i) acc0[k] = fmaf(w0[i], xv[i], acc0[k]);
      #pragma unroll
      for (int i = 0; i < 8; ++i) acc1[k] = fmaf(w1v[i], xv[i], acc1[k]);
    }
  }
  double s0 = 0., q0 = 0., s1 = 0., q1 = 0.;
  __hip_bfloat16* hb = h3 + (size_t)p * K * C3;
  #pragma unroll
  for (int k = 0; k < K; ++k) {
    double h0 = (double)acc0[k]; s0 += h0; q0 += h0*h0;
    double h1 = (double)acc1[k]; s1 += h1; q1 += h1*h1;
    hb[k*C3 + tid] = __float2bfloat16(acc0[k]);
    hb[k*C3 + tid + 128] = __float2bfloat16(acc1[k]);
  }
  int slice = p & (NSLICE - 1);
  atomicAdd(&sS[slice*C3 + tid], s0);
  atomicAdd(&sQ[slice*C3 + tid], q0);
  atomicAdd(&sS[slice*C3 + tid + 128], s1);
  atomicAdd(&sQ[slice*C3 + tid + 128], q1);
}

// ---- conv3 pass1: load bf16 h3 + BN + max (r6-proven math) ----
__global__ __launch_bounds__(256, 1) void conv3_p1_load(
    const __hip_bfloat16* __restrict__ h3, const double* __restrict__ mid,
    const float* __restrict__ gam, const float* __restrict__ bet,
    float* __restrict__ out448) {
  int p = blockIdx.x;
  int o = threadIdx.x;
  float m = (float)mid[o], is = (float)mid[C3 + o];
  float g = gam[o], bb = bet[o];
  const __hip_bfloat16* hb = h3 + (size_t)p * K * C3;
  float mxv = -INFINITY;
  #pragma unroll
  for (int k = 0; k < K; ++k) {
    float h = __bfloat162float(hb[k*C3 + o]);
    float y = (h - m) * is * g + bb;
    y = y > 0.f ? y : 0.2f * y;
    mxv = fmaxf(mxv, y);
  }
  out448[(size_t)p*448 + C1 + C2 + o] = mxv;
}

// ---- finalize BN stats (f64) ----
__global__ void finalize_stats(const double* __restrict__ sS, const double* __restrict__ sQ,
                               double* __restrict__ mid, int C) {
  int o = threadIdx.x;
  if (o >= C) return;
  double s = 0., q = 0.;
  for (int i = 0; i < NSLICE; ++i) { s += sS[i*C3 + o]; q += sQ[i*C3 + o]; }
  double m = s / COUNT;
  double v = q / COUNT - m*m;
  mid[o] = m;
  mid[C3 + o] = 1.0 / sqrt(v + BNEPS);
}

} // namespace

extern "C" void kernel_launch(void* const* d_in, const int* in_sizes, int n_in,
                              void* d_out, int out_size, void* d_ws, size_t ws_size,
                              hipStream_t stream) {
  (void)in_sizes; (void)n_in; (void)out_size; (void)ws_size;
  const float* x   = (const float*)d_in[0];
  const float* nrm = (const float*)d_in[1];
  const float* w1  = (const float*)d_in[2];
  const float* g1  = (const float*)d_in[3];
  const float* b1  = (const float*)d_in[4];
  const float* w2  = (const float*)d_in[5];
  const float* g2  = (const float*)d_in[6];
  const float* b2  = (const float*)d_in[7];
  const float* w3  = (const float*)d_in[8];
  const float* g3  = (const float*)d_in[9];
  const float* b3  = (const float*)d_in[10];
  float* out = (float*)d_out;
  char*  ws  = (char*)d_ws;

  int*    idx1 = (int*)(ws + OFF_IDX1);
  int*    idx2 = (int*)(ws + OFF_IDX2);
  double* x1d  = (double*)(ws + OFF_X1D);
  double* x2d  = (double*)(ws + OFF_X2D);
  double* sS   = (double*)(ws + OFF_STATS);
  double* sQ   = sS + (size_t)NSLICE * C3;
  double* mid  = (double*)(ws + OFF_MI);
  float*  x2f  = (float*)(ws + OFF_X2F);
  float*  xx2f = (float*)(ws + OFF_XX2F);
  char*   big  = ws + OFF_BIG;
  float*  dist = (float*)big;                 // live: dist_f32 .. knn_feat
  __hip_bfloat16* h3 = (__hip_bfloat16*)big;  // live: conv3_p0 .. conv3_p1 (dist dead)

  float* outR1 = out + (size_t)B * N * 448;
  float* outR2 = outR1 + (size_t)B * N * 9;

  // kNN1 — numpy-f32-faithful formula
  knn_xyz_f32<<<B*N/64, 64, 0, stream>>>(x, idx1);

  // layer 1 (f64 two-pass)
  hipMemsetAsync(sS, 0, (size_t)2*NSLICE*C3*sizeof(double), stream);
  l1_kernel<0><<<B*N, 64, 0, stream>>>(x, nrm, w1, idx1, sS, sQ, nullptr, nullptr, nullptr,
                                       nullptr, nullptr, outR1, outR2);
  finalize_stats<<<1, C3, 0, stream>>>(sS, sQ, mid, C1);
  l1_kernel<1><<<B*N, 64, 0, stream>>>(x, nrm, w1, idx1, nullptr, nullptr, mid, g1, b1,
                                       x1d, out, outR1, outR2);

  // layer 2 (f64 two-pass recompute, bit-exact op order)
  hipMemsetAsync(sS, 0, (size_t)2*NSLICE*C3*sizeof(double), stream);
  conv2_full<0><<<B*N, 128, 0, stream>>>(x1d, idx1, w2, sS, sQ, nullptr, nullptr, nullptr,
                                         nullptr, nullptr);
  finalize_stats<<<1, C3, 0, stream>>>(sS, sQ, mid, C2);
  conv2_full<1><<<B*N, 128, 0, stream>>>(x1d, idx1, w2, nullptr, nullptr, mid, g2, b2,
                                         x2d, out);

  // kNN2 — numpy-f32-faithful, all batches fused; wave-parallel coalesced top-k
  xx2f_kernel<<<B*N/64, 64, 0, stream>>>(x2d, x2f, xx2f);
  dist_f32_kernel<<<dim3(N/64, N/64, B), 256, 0, stream>>>(x2f, xx2f, dist);
  knn_feat_wave<<<B*N/4, 256, 0, stream>>>(dist, idx2);

  // layer 3 (f32 conv once + bf16 h3 in dead dist region + light BN/max)
  hipMemsetAsync(sS, 0, (size_t)2*NSLICE*C3*sizeof(double), stream);
  conv3_p0_store<<<B*N, 128, 0, stream>>>(x2f, idx2, w3, sS, sQ, h3);
  finalize_stats<<<1, C3, 0, stream>>>(sS, sQ, mid, C3);
  conv3_p1_load<<<B*N, 256, 0, stream>>>(h3, mid, g3, b3, out);
}

// Round 12
// 2215.378 us; speedup vs baseline: 2.4698x; 1.4386x over previous
//
#include <hip/hip_runtime.h>
#include <hip/hip_bf16.h>
#include <math.h>

namespace {

constexpr int B  = 8;
constexpr int N  = 2048;     // power of two: n = p & 2047, b = p >> 11
constexpr int K  = 20;
constexpr int C1 = 64, C2 = 128, C3 = 256;
constexpr int NSLICE = 64;
constexpr double COUNT = 327680.0;   // B*N*K
constexpr double BNEPS = 1e-5;

// ---- workspace layout (bytes) ----
constexpr size_t OFF_IDX1  = 0;                                  // B*N*K int
constexpr size_t OFF_IDX2  = OFF_IDX1 + (size_t)B*N*K*4;         // B*N*K int
constexpr size_t OFF_X1D   = OFF_IDX2 + (size_t)B*N*K*4;         // B*N*C1 f64
constexpr size_t OFF_X2D   = OFF_X1D  + (size_t)B*N*C1*8;        // B*N*C2 f64
constexpr size_t OFF_STATS = OFF_X2D  + (size_t)B*N*C2*8;        // 2*NSLICE*C3 f64
constexpr size_t OFF_MI    = OFF_STATS+ (size_t)2*NSLICE*C3*8;   // 2*C3 f64
constexpr size_t OFF_X2F   = OFF_MI   + 4096;                    // B*N*C2 f32
constexpr size_t OFF_XX2F  = OFF_X2F  + (size_t)B*N*C2*4;        // B*N f32
constexpr size_t OFF_BIG   = OFF_XX2F + (size_t)B*N*4;           // shared big region
// big region, strictly sequential lifetimes:
//   dist f32 (134.2 MB)  ->  h3 bf16 (83.9 MB)
// footprint = OFF_BIG + 134.2 MB (proven to fit since round 7).

// ---- strict-rounding f32 helpers (block FMA contraction / reassociation) ----
__device__ __forceinline__ float fmul32(float a, float b){ return __fmul_rn(a,b); }
__device__ __forceinline__ float fadd32(float a, float b){ return __fadd_rn(a,b); }
__device__ __forceinline__ float fsub32(float a, float b){ return __fsub_rn(a,b); }

// ---- per-thread insertion top-20 on f32 (largest, ties keep lowest index) ----
__device__ __forceinline__ void insert_candidatef(float v, int j,
                                                  float (&best)[K], int (&bidx)[K]) {
  if (v > best[K-1]) {
    best[K-1] = v; bidx[K-1] = j;
    #pragma unroll
    for (int i = K-1; i >= 1; --i) {
      if (best[i] > best[i-1]) {
        float tv = best[i]; best[i] = best[i-1]; best[i-1] = tv;
        int   ti = bidx[i]; bidx[i] = bidx[i-1]; bidx[i-1] = ti;
      }
    }
  }
}

// ---- kNN on 3-D coords, numpy-f32-faithful (BIT-FROZEN) ----
__global__ __launch_bounds__(64) void knn_xyz_f32(const float* __restrict__ x,
                                                  int* __restrict__ idxo) {
  int row = blockIdx.x * 64 + threadIdx.x;   // grid = B*N/64
  int b = row >> 11, n = row & (N - 1);
  const float* xb = x + (size_t)b * N * 3;
  float xi0 = xb[(size_t)n*3], xi1 = xb[(size_t)n*3+1], xi2 = xb[(size_t)n*3+2];
  float xxi = fadd32(fadd32(fmul32(xi0,xi0), fmul32(xi1,xi1)), fmul32(xi2,xi2));
  float best[K]; int bidx[K];
  #pragma unroll
  for (int i = 0; i < K; ++i) { best[i] = -INFINITY; bidx[i] = 0; }
  for (int j = 0; j < N; ++j) {
    float a = xb[(size_t)j*3], c = xb[(size_t)j*3+1], d = xb[(size_t)j*3+2];
    float xxj   = fadd32(fadd32(fmul32(a,a), fmul32(c,c)), fmul32(d,d));
    float inner = fadd32(fadd32(fmul32(xi0,a), fmul32(xi1,c)), fmul32(xi2,d));
    float v = fsub32(fsub32(fmul32(2.f, inner), xxi), xxj);
    insert_candidatef(v, j, best, bidx);
  }
  int* o = idxo + (size_t)row * K;
  #pragma unroll
  for (int i = 0; i < K; ++i) o[i] = bidx[i];
}

// ---- x2 -> f32 copy + numpy pairwise(n=128) sum of squares (BIT-FROZEN) ----
__global__ __launch_bounds__(64) void xx2f_kernel(const double* __restrict__ x2d,
                                                  float* __restrict__ x2f,
                                                  float* __restrict__ xx2f) {
  int row = blockIdx.x * 64 + threadIdx.x;   // grid = B*N/64
  const double* src = x2d + (size_t)row * C2;
  float* dst = x2f + (size_t)row * C2;
  float sq[C2];
  #pragma unroll 8
  for (int c = 0; c < C2; ++c) {
    float v = (float)src[c];
    dst[c] = v;
    sq[c] = fmul32(v, v);
  }
  float r0=sq[0], r1=sq[1], r2=sq[2], r3=sq[3], r4=sq[4], r5=sq[5], r6=sq[6], r7=sq[7];
  #pragma unroll
  for (int i = 8; i < 128; i += 8) {
    r0 = fadd32(r0, sq[i+0]); r1 = fadd32(r1, sq[i+1]);
    r2 = fadd32(r2, sq[i+2]); r3 = fadd32(r3, sq[i+3]);
    r4 = fadd32(r4, sq[i+4]); r5 = fadd32(r5, sq[i+5]);
    r6 = fadd32(r6, sq[i+6]); r7 = fadd32(r7, sq[i+7]);
  }
  xx2f[row] = fadd32(fadd32(fadd32(r0,r1), fadd32(r2,r3)),
                     fadd32(fadd32(r4,r5), fadd32(r6,r7)));
}

// ---- all-batch neg-distance matrix, f32 sequential (BIT-FROZEN inner) ----
__global__ __launch_bounds__(256) void dist_f32_kernel(const float* __restrict__ x2f,
                                                       const float* __restrict__ xx2f,
                                                       float* __restrict__ dist) {
  int bz = blockIdx.z;
  const float* x2b  = x2f  + (size_t)bz * N * C2;
  const float* xx2b = xx2f + (size_t)bz * N;
  float* db = dist + (size_t)bz * N * N;
  int ti = blockIdx.y * 64;
  int tj = blockIdx.x * 64;
  int tid = threadIdx.x;
  int tr = tid >> 4, tc = tid & 15;
  __shared__ float A[64][9], Bm[64][9];
  float acc[4][4];
  #pragma unroll
  for (int u = 0; u < 4; ++u)
    #pragma unroll
    for (int v = 0; v < 4; ++v) acc[u][v] = 0.f;
  for (int c0 = 0; c0 < C2; c0 += 8) {
    for (int i = tid; i < 512; i += 256) {
      int r = i >> 3, c = i & 7;
      A[r][c]  = x2b[(size_t)(ti + r)*C2 + c0 + c];
      Bm[r][c] = x2b[(size_t)(tj + r)*C2 + c0 + c];
    }
    __syncthreads();
    #pragma unroll
    for (int c = 0; c < 8; ++c) {       // ascending c: exact sequential order
      float a[4], bv[4];
      #pragma unroll
      for (int u = 0; u < 4; ++u) a[u] = A[tr*4 + u][c];
      #pragma unroll
      for (int v = 0; v < 4; ++v) bv[v] = Bm[tc*4 + v][c];
      #pragma unroll
      for (int u = 0; u < 4; ++u)
        #pragma unroll
        for (int v = 0; v < 4; ++v)
          acc[u][v] = fadd32(acc[u][v], fmul32(a[u], bv[v]));
    }
    __syncthreads();
  }
  #pragma unroll
  for (int u = 0; u < 4; ++u) {
    int i = ti + tr*4 + u;
    float xxi = xx2b[i];
    #pragma unroll
    for (int v = 0; v < 4; ++v) {
      int j = tj + tc*4 + v;
      db[(size_t)i*N + j] = fsub32(fsub32(fmul32(2.f, acc[u][v]), xxi), xx2b[j]);
    }
  }
}

// ---- wave-parallel top-20 on frozen dist values (coalesced reads).
// Comparator identical to insertion version: value desc, ties -> smaller index.
__global__ __launch_bounds__(256) void knn_feat_wave(const float* __restrict__ dist,
                                                     int* __restrict__ idxo) {
  int row  = blockIdx.x * 4 + (threadIdx.x >> 6);   // grid = B*N/4
  int lane = threadIdx.x & 63;
  const float* dr = dist + (size_t)row * N;
  float vals[32];
  #pragma unroll
  for (int t = 0; t < 32; ++t) vals[t] = dr[lane + (t << 6)];   // coalesced
  int* out = idxo + (size_t)row * K;
  for (int sel = 0; sel < K; ++sel) {
    float best = -INFINITY; int bt = 0;
    #pragma unroll
    for (int t = 0; t < 32; ++t)
      if (vals[t] > best) { best = vals[t]; bt = t; }   // local ties -> smaller t (smaller idx)
    int bcol = lane + (bt << 6);
    #pragma unroll
    for (int off = 32; off >= 1; off >>= 1) {
      float ov = __shfl_xor(best, off, 64);
      int   oc = __shfl_xor(bcol, off, 64);
      if (ov > best || (ov == best && oc < bcol)) { best = ov; bcol = oc; }
    }
    if (lane == 0) out[sel] = bcol;
    int kill = ((bcol & 63) == lane) ? (bcol >> 6) : 32;
    #pragma unroll
    for (int t = 0; t < 32; ++t) if (t == kill) vals[t] = -INFINITY;
  }
}

// ---- layer 1 (two-pass, f64): geometry + conv1 (BIT-FROZEN) ----
template<int PASS>
__global__ __launch_bounds__(64) void l1_kernel(
    const float* __restrict__ x, const float* __restrict__ nrm,
    const float* __restrict__ w1, const int* __restrict__ idx1,
    double* __restrict__ sS, double* __restrict__ sQ,
    const double* __restrict__ mid, const float* __restrict__ g1, const float* __restrict__ b1,
    double* __restrict__ x1d, float* __restrict__ out448,
    float* __restrict__ outR1, float* __restrict__ outR2) {
  int p = blockIdx.x;
  int tid = threadIdx.x;
  int b = p >> 11, n = p & (N - 1);
  __shared__ float  wl[C1 * 9];
  __shared__ double rotd[K][3];
  __shared__ double fld[K][9];
  for (int i = tid; i < C1 * 9; i += 64) wl[i] = w1[i];
  const float* xb = x + (size_t)b * N * 3;
  double nx = nrm[(size_t)p*3], ny = nrm[(size_t)p*3+1], nz = nrm[(size_t)p*3+2];
  double vx = ny, vy = -nx;
  double s = 1.0 / fmax(1.0 + nz, 1e-8);
  double vxy = vx * vy;
  double R1v[9];
  R1v[0] = 1.0 - s*(vy*vy); R1v[1] = s*vxy;           R1v[2] = vy;
  R1v[3] = s*vxy;           R1v[4] = 1.0 - s*(vx*vx); R1v[5] = -vx;
  R1v[6] = -vy;             R1v[7] = vx;              R1v[8] = 1.0 - s*(vx*vx + vy*vy);
  double xi0 = xb[(size_t)n*3], xi1 = xb[(size_t)n*3+1], xi2 = xb[(size_t)n*3+2];
  if (tid < K) {
    int j = idx1[(size_t)p*K + tid];
    double d0 = (double)xb[(size_t)j*3]   - xi0;
    double d1 = (double)xb[(size_t)j*3+1] - xi1;
    double d2 = (double)xb[(size_t)j*3+2] - xi2;
    rotd[tid][0] = R1v[0]*d0 + R1v[1]*d1 + R1v[2]*d2;
    rotd[tid][1] = R1v[3]*d0 + R1v[4]*d1 + R1v[5]*d2;
    rotd[tid][2] = R1v[6]*d0 + R1v[7]*d1 + R1v[8]*d2;
  }
  __syncthreads();
  double mx = 0.0, my = 0.0;
  #pragma unroll
  for (int k = 0; k < K; ++k) { mx += rotd[k][0]; my += rotd[k][1]; }
  mx /= 20.0; my /= 20.0;
  double r = sqrt(mx*mx + my*my);
  double ct = 1.0, st = 0.0;
  if (r > 0.0) { ct = mx / r; st = my / r; }   // cos/sin of atan2(my,mx)
  if (tid < K) {
    double r0 = rotd[tid][0], r1 = rotd[tid][1], r2 = rotd[tid][2];
    double a0 = ct*r0 + st*r1;
    double a1 = ct*r1 - st*r0;
    fld[tid][0] = a0;  fld[tid][1] = a1;   fld[tid][2] = r2;
    fld[tid][3] = a0;  fld[tid][4] = -a1;  fld[tid][5] = r2;   // xz-mirror
    fld[tid][6] = xi0; fld[tid][7] = xi1;  fld[tid][8] = xi2;  // x_rep
  }
  if (PASS == 0 && tid == 0) {
    float* o1 = outR1 + (size_t)p * 9;
    #pragma unroll
    for (int i = 0; i < 9; ++i) o1[i] = (float)R1v[i];
    float* o2 = outR2 + (size_t)p * 9;
    o2[0] = (float)ct;  o2[1] = (float)st; o2[2] = 0.f;
    o2[3] = (float)-st; o2[4] = (float)ct; o2[5] = 0.f;
    o2[6] = 0.f;        o2[7] = 0.f;       o2[8] = 1.f;
  }
  __syncthreads();
  int o = tid;
  if (PASS == 0) {
    double sum = 0., sq = 0.;
    #pragma unroll
    for (int k = 0; k < K; ++k) {
      double h = 0.;
      #pragma unroll
      for (int c = 0; c < 9; ++c) h = fma((double)wl[o*9 + c], fld[k][c], h);
      sum += h; sq += h*h;
    }
    int slice = p & (NSLICE - 1);
    atomicAdd(&sS[slice*C3 + o], sum);
    atomicAdd(&sQ[slice*C3 + o], sq);
  } else {
    double m = mid[o], is = mid[C3 + o];
    double g = g1[o], bb = b1[o];
    double mxv = -INFINITY;
    #pragma unroll
    for (int k = 0; k < K; ++k) {
      double h = 0.;
      #pragma unroll
      for (int c = 0; c < 9; ++c) h = fma((double)wl[o*9 + c], fld[k][c], h);
      double y = ((h - m) * is) * g + bb;
      y = y > 0.0 ? y : 0.2 * y;
      mxv = fmax(mxv, y);
    }
    x1d[(size_t)p*C1 + o] = mxv;
    out448[(size_t)p*448 + o] = (float)mxv;
  }
}

// ---- conv2 core: exact round-8 op sequence, 128 threads, NOUT=1 (BIT-FROZEN) ----
__device__ __forceinline__ void conv2_core(const double* __restrict__ x1d,
                                           const int* __restrict__ idx,
                                           const float* __restrict__ w,
                                           int p, int tid, double (&acc)[K]) {
  int b = p >> 11;
  __shared__ double difL[K][C1];
  __shared__ double xiL[C1];
  __shared__ int jidx[K];
  if (tid < K) jidx[tid] = idx[(size_t)p*K + tid];
  if (tid < C1) xiL[tid] = x1d[(size_t)p*C1 + tid];
  __syncthreads();
  #pragma unroll 1
  for (int i = tid; i < K*C1; i += 128) {
    int k = i >> 6, c = i & 63;
    difL[k][c] = x1d[((size_t)b*N + jidx[k])*C1 + c] - xiL[c];
  }
  __syncthreads();
  const float* wr = w + (size_t)tid * (2*C1);
  #pragma unroll
  for (int k = 0; k < K; ++k) acc[k] = 0.0;
  // phase 1: diff operand, c ascending per acc
  #pragma unroll
  for (int c0 = 0; c0 < C1; c0 += 16) {
    double wd[16];
    #pragma unroll
    for (int i = 0; i < 16; ++i) wd[i] = (double)wr[c0+i];
    #pragma unroll
    for (int k = 0; k < K; ++k) {
      #pragma unroll
      for (int i = 0; i < 16; ++i) acc[k] = fma(wd[i], difL[k][c0+i], acc[k]);
    }
  }
  // phase 2: x_rep operand, c ascending per acc
  #pragma unroll
  for (int c0 = 0; c0 < C1; c0 += 16) {
    double wd[16], xiv[16];
    #pragma unroll
    for (int i = 0; i < 16; ++i) { wd[i] = (double)wr[C1+c0+i]; xiv[i] = xiL[c0+i]; }
    #pragma unroll
    for (int k = 0; k < K; ++k) {
      #pragma unroll
      for (int i = 0; i < 16; ++i) acc[k] = fma(wd[i], xiv[i], acc[k]);
    }
  }
}

// ---- conv2 (two-pass recompute, round-8 proven) ----
template<int PASS>
__global__ __launch_bounds__(128, 1) void conv2_full(
    const double* __restrict__ x1d, const int* __restrict__ idx,
    const float* __restrict__ w,
    double* __restrict__ sS, double* __restrict__ sQ,
    const double* __restrict__ mid, const float* __restrict__ gam, const float* __restrict__ bet,
    double* __restrict__ x2d, float* __restrict__ out448) {
  int p = blockIdx.x;
  int tid = threadIdx.x;
  double acc[K];
  conv2_core(x1d, idx, w, p, tid, acc);
  if (PASS == 0) {
    double sum = 0., sq = 0.;
    #pragma unroll
    for (int k = 0; k < K; ++k) { sum += acc[k]; sq += acc[k]*acc[k]; }
    int slice = p & (NSLICE - 1);
    atomicAdd(&sS[slice*C3 + tid], sum);
    atomicAdd(&sQ[slice*C3 + tid], sq);
  } else {
    double m = mid[tid], is = mid[C3 + tid];
    double g = gam[tid], bb = bet[tid];
    double mxv = -INFINITY;
    #pragma unroll
    for (int k = 0; k < K; ++k) {
      double y = ((acc[k] - m) * is) * g + bb;
      y = y > 0.0 ? y : 0.2 * y;
      mxv = fmax(mxv, y);
    }
    x2d[(size_t)p*C2 + tid] = mxv;
    out448[(size_t)p*448 + C1 + tid] = (float)mxv;
  }
}

// ---- conv3 pass0: 256 threads, NOUT=1 (r8/r10-proven codegen: VGPR~80, no
// spill) — conv ONCE + stats + bf16 h3 store (tid-contiguous, coalesced). ----
__global__ __launch_bounds__(256, 1) void conv3_p0_store(
    const float* __restrict__ x2f, const int* __restrict__ idx,
    const float* __restrict__ w,
    double* __restrict__ sS, double* __restrict__ sQ,
    __hip_bfloat16* __restrict__ h3) {
  int p = blockIdx.x;
  int tid = threadIdx.x;
  int b = p >> 11;
  __shared__ float xjL[K][C2];
  __shared__ float xiL[C2];
  __shared__ int jidx[K];
  if (tid < K) jidx[tid] = idx[(size_t)p*K + tid];
  if (tid < C2) xiL[tid] = x2f[(size_t)p*C2 + tid];
  __syncthreads();
  #pragma unroll 1
  for (int i = tid; i < K*C2; i += 256) {
    int k = i >> 7, c = i & 127;
    xjL[k][c] = x2f[((size_t)b*N + jidx[k])*C2 + c];
  }
  __syncthreads();
  const float* wr = w + (size_t)tid * (2*C2);
  float base = 0.f;
  #pragma unroll
  for (int c0 = 0; c0 < C2; c0 += 32) {
    #pragma unroll
    for (int i = 0; i < 32; ++i)
      base = fmaf(wr[C2+c0+i] - wr[c0+i], xiL[c0+i], base);
  }
  float acc[K];
  #pragma unroll
  for (int k = 0; k < K; ++k) acc[k] = base;
  #pragma unroll
  for (int c0 = 0; c0 < C2; c0 += 32) {
    float wd[32];
    #pragma unroll
    for (int i = 0; i < 32; ++i) wd[i] = wr[c0+i];
    #pragma unroll
    for (int k = 0; k < K; ++k) {
      #pragma unroll
      for (int i = 0; i < 32; ++i) acc[k] = fmaf(wd[i], xjL[k][c0+i], acc[k]);
    }
  }
  double sum = 0., sq = 0.;
  __hip_bfloat16* hb = h3 + (size_t)p * K * C3;
  #pragma unroll
  for (int k = 0; k < K; ++k) {
    double h = (double)acc[k];
    sum += h; sq += h*h;
    hb[k*C3 + tid] = __float2bfloat16(acc[k]);
  }
  int slice = p & (NSLICE - 1);
  atomicAdd(&sS[slice*C3 + tid], sum);
  atomicAdd(&sQ[slice*C3 + tid], sq);
}

// ---- conv3 pass1: load bf16 h3 + BN + max (r6/r11-proven math) ----
__global__ __launch_bounds__(256, 1) void conv3_p1_load(
    const __hip_bfloat16* __restrict__ h3, const double* __restrict__ mid,
    const float* __restrict__ gam, const float* __restrict__ bet,
    float* __restrict__ out448) {
  int p = blockIdx.x;
  int o = threadIdx.x;
  float m = (float)mid[o], is = (float)mid[C3 + o];
  float g = gam[o], bb = bet[o];
  const __hip_bfloat16* hb = h3 + (size_t)p * K * C3;
  float mxv = -INFINITY;
  #pragma unroll
  for (int k = 0; k < K; ++k) {
    float h = __bfloat162float(hb[k*C3 + o]);
    float y = (h - m) * is * g + bb;
    y = y > 0.f ? y : 0.2f * y;
    mxv = fmaxf(mxv, y);
  }
  out448[(size_t)p*448 + C1 + C2 + o] = mxv;
}

// ---- finalize BN stats (f64) ----
__global__ void finalize_stats(const double* __restrict__ sS, const double* __restrict__ sQ,
                               double* __restrict__ mid, int C) {
  int o = threadIdx.x;
  if (o >= C) return;
  double s = 0., q = 0.;
  for (int i = 0; i < NSLICE; ++i) { s += sS[i*C3 + o]; q += sQ[i*C3 + o]; }
  double m = s / COUNT;
  double v = q / COUNT - m*m;
  mid[o] = m;
  mid[C3 + o] = 1.0 / sqrt(v + BNEPS);
}

} // namespace

extern "C" void kernel_launch(void* const* d_in, const int* in_sizes, int n_in,
                              void* d_out, int out_size, void* d_ws, size_t ws_size,
                              hipStream_t stream) {
  (void)in_sizes; (void)n_in; (void)out_size; (void)ws_size;
  const float* x   = (const float*)d_in[0];
  const float* nrm = (const float*)d_in[1];
  const float* w1  = (const float*)d_in[2];
  const float* g1  = (const float*)d_in[3];
  const float* b1  = (const float*)d_in[4];
  const float* w2  = (const float*)d_in[5];
  const float* g2  = (const float*)d_in[6];
  const float* b2  = (const float*)d_in[7];
  const float* w3  = (const float*)d_in[8];
  const float* g3  = (const float*)d_in[9];
  const float* b3  = (const float*)d_in[10];
  float* out = (float*)d_out;
  char*  ws  = (char*)d_ws;

  int*    idx1 = (int*)(ws + OFF_IDX1);
  int*    idx2 = (int*)(ws + OFF_IDX2);
  double* x1d  = (double*)(ws + OFF_X1D);
  double* x2d  = (double*)(ws + OFF_X2D);
  double* sS   = (double*)(ws + OFF_STATS);
  double* sQ   = sS + (size_t)NSLICE * C3;
  double* mid  = (double*)(ws + OFF_MI);
  float*  x2f  = (float*)(ws + OFF_X2F);
  float*  xx2f = (float*)(ws + OFF_XX2F);
  char*   big  = ws + OFF_BIG;
  float*  dist = (float*)big;                 // live: dist_f32 .. knn_feat
  __hip_bfloat16* h3 = (__hip_bfloat16*)big;  // live: conv3_p0 .. conv3_p1 (dist dead)

  float* outR1 = out + (size_t)B * N * 448;
  float* outR2 = outR1 + (size_t)B * N * 9;

  // kNN1 — numpy-f32-faithful formula
  knn_xyz_f32<<<B*N/64, 64, 0, stream>>>(x, idx1);

  // layer 1 (f64 two-pass)
  hipMemsetAsync(sS, 0, (size_t)2*NSLICE*C3*sizeof(double), stream);
  l1_kernel<0><<<B*N, 64, 0, stream>>>(x, nrm, w1, idx1, sS, sQ, nullptr, nullptr, nullptr,
                                       nullptr, nullptr, outR1, outR2);
  finalize_stats<<<1, C3, 0, stream>>>(sS, sQ, mid, C1);
  l1_kernel<1><<<B*N, 64, 0, stream>>>(x, nrm, w1, idx1, nullptr, nullptr, mid, g1, b1,
                                       x1d, out, outR1, outR2);

  // layer 2 (f64 two-pass recompute, bit-exact op order)
  hipMemsetAsync(sS, 0, (size_t)2*NSLICE*C3*sizeof(double), stream);
  conv2_full<0><<<B*N, 128, 0, stream>>>(x1d, idx1, w2, sS, sQ, nullptr, nullptr, nullptr,
                                         nullptr, nullptr);
  finalize_stats<<<1, C3, 0, stream>>>(sS, sQ, mid, C2);
  conv2_full<1><<<B*N, 128, 0, stream>>>(x1d, idx1, w2, nullptr, nullptr, mid, g2, b2,
                                         x2d, out);

  // kNN2 — numpy-f32-faithful, all batches fused; wave-parallel coalesced top-k
  xx2f_kernel<<<B*N/64, 64, 0, stream>>>(x2d, x2f, xx2f);
  dist_f32_kernel<<<dim3(N/64, N/64, B), 256, 0, stream>>>(x2f, xx2f, dist);
  knn_feat_wave<<<B*N/4, 256, 0, stream>>>(dist, idx2);

  // layer 3 (f32 conv once + bf16 h3 in dead dist region + light BN/max)
  hipMemsetAsync(sS, 0, (size_t)2*NSLICE*C3*sizeof(double), stream);
  conv3_p0_store<<<B*N, 256, 0, stream>>>(x2f, idx2, w3, sS, sQ, h3);
  finalize_stats<<<1, C3, 0, stream>>>(sS, sQ, mid, C3);
  conv3_p1_load<<<B*N, 256, 0, stream>>>(h3, mid, g3, b3, out);
}